// Round 6
// baseline (1159.786 us; speedup 1.0000x reference)
//
#include <hip/hip_runtime.h>
#include <hip/hip_bf16.h>
#include <math.h>

// ---------------------------------------------------------------------------
// DeepSeek MLA forward. Round 6:
//  - Attention: split-K flash-decoding. 1280 blocks = 16 heads x 80 (qt,slice);
//    each block does <=4 k-tiles of 128 keys; partial (O bf16, m, l) to ws;
//    merge kernel combines. LDS 35 KB -> 4 blocks/CU; Ps padded (stride 72)
//    to kill the 16-way bank conflicts round 5 had.
//  - out-GEMM: post-softmax => plain bf16 single-MFMA (m97 structure);
//    attention partials + y are bf16 (error ~0.3% << 2% threshold).
//  - Score path (q, kn, kpe, and their producer GEMMs) stays split-bf16
//    3-MFMA (fp32-equivalent).
// ---------------------------------------------------------------------------

#define T_DIM 2048
#define HEADS 16
#define D_MODEL 2048
#define NOPE_D 128
#define ROPE_D 64
#define QKD_D 192
#define VD_D 128
#define QLORA 768
#define KVLORA 512
#define KVFULL_D 576
#define SOFTSCALE -96.0f
#define EPS_RMS 1e-6f

typedef __hip_bfloat16 bf;
typedef __attribute__((ext_vector_type(8))) short bf16x8;
typedef __attribute__((ext_vector_type(4))) float f32x4;

#define SLICE_BYTES 16896   // O 64x128 bf16 (16384) + m 64 f32 + l 64 f32
#define PART1_CAP 992       // slices in 16.78 MB arena

#define GLOAD_LDS16(gptr, lptr)                                               \
    __builtin_amdgcn_global_load_lds(                                         \
        (const __attribute__((address_space(1))) unsigned int*)(gptr),        \
        (__attribute__((address_space(3))) unsigned int*)(lptr), 16, 0, 0)

__device__ __forceinline__ void split2(float v, bf* hi, bf* lo) {
    bf h = __float2bfloat16(v);
    *hi = h;
    *lo = __float2bfloat16(v - __bfloat162float(h));
}

// ---------------------------------------------------------------------------
__global__ __launch_bounds__(256) void cvt_split(
    const float* __restrict__ in, bf* __restrict__ hi, bf* __restrict__ lo, int n)
{
    const int i = (blockIdx.x * 256 + threadIdx.x) * 4;
    if (i >= n) return;
    float4 v = *(const float4*)&in[i];
    float vv[4] = {v.x, v.y, v.z, v.w};
#pragma unroll
    for (int u = 0; u < 4; u++) split2(vv[u], &hi[i + u], &lo[i + u]);
}

__global__ __launch_bounds__(256) void cvt_hi(
    const float* __restrict__ in, bf* __restrict__ hi, int n)
{
    const int i = (blockIdx.x * 256 + threadIdx.x) * 4;
    if (i >= n) return;
    float4 v = *(const float4*)&in[i];
    hi[i + 0] = __float2bfloat16(v.x);
    hi[i + 1] = __float2bfloat16(v.y);
    hi[i + 2] = __float2bfloat16(v.z);
    hi[i + 3] = __float2bfloat16(v.w);
}

// ---------------------------------------------------------------------------
__global__ __launch_bounds__(256) void rmsnorm_cvt(
    const float* __restrict__ in, int ld, int D, const float* __restrict__ w,
    bf* __restrict__ hi, bf* __restrict__ lo)
{
    const int row = blockIdx.x;
    const float* r = in + (size_t)row * ld;
    float ss = 0.0f;
    for (int i = threadIdx.x; i < D; i += 256) { float v = r[i]; ss += v * v; }
#pragma unroll
    for (int o = 32; o > 0; o >>= 1) ss += __shfl_down(ss, o, 64);
    __shared__ float red[4];
    if ((threadIdx.x & 63) == 0) red[threadIdx.x >> 6] = ss;
    __syncthreads();
    ss = red[0] + red[1] + red[2] + red[3];
    const float scale = rsqrtf(ss / (float)D + EPS_RMS);
    for (int i = threadIdx.x; i < D; i += 256) {
        const float v = r[i] * scale * w[i];
        split2(v, &hi[(size_t)row * D + i], &lo[(size_t)row * D + i]);
    }
}

// ---------------------------------------------------------------------------
__global__ __launch_bounds__(256) void rope_k_cvt(
    const float* __restrict__ kvfull, const float* __restrict__ freqs,
    bf* __restrict__ kpeh, bf* __restrict__ kpel)
{
    const int idx = blockIdx.x * 256 + threadIdx.x;   // 65536
    const int i = idx & 31, t = idx >> 5;
    const float f = freqs[t * 32 + i];
    float sn, cs; sincosf(f, &sn, &cs);
    const float x1 = kvfull[(size_t)t * KVFULL_D + KVLORA + 2 * i];
    const float x2 = kvfull[(size_t)t * KVFULL_D + KVLORA + 2 * i + 1];
    split2(x1 * cs - x2 * sn, &kpeh[t * 64 + 2 * i], &kpel[t * 64 + 2 * i]);
    split2(x1 * sn + x2 * cs, &kpeh[t * 64 + 2 * i + 1], &kpel[t * 64 + 2 * i + 1]);
}

// ---------------------------------------------------------------------------
__global__ __launch_bounds__(256) void transpose_v(
    const bf* __restrict__ vh, bf* __restrict__ vT)
{
    __shared__ bf s[32][33];
    const int t0 = blockIdx.x * 32, d0 = blockIdx.y * 32, h = blockIdx.z;
    const int tid = threadIdx.x;
    const int i = tid >> 3, j0 = (tid & 7) * 4;
    const bf* src = vh + ((size_t)(t0 + i) * 16 + h) * 128 + d0 + j0;
#pragma unroll
    for (int u = 0; u < 4; u++) s[i][j0 + u] = src[u];
    __syncthreads();
    const int jj = tid >> 3, i0 = (tid & 7) * 4;
    bf* dst = vT + ((size_t)h * 128 + d0 + jj) * 2048 + t0 + i0;
#pragma unroll
    for (int u = 0; u < 4; u++) dst[u] = s[i0 + u][jj];
}

// ---------------------------------------------------------------------------
// Split-bf16 GEMM (score path), 128x128 tile, 3 MFMAs. MODE 0: C fp32
// (+N guard). MODE 1: RoPE on d>=128 + split -> Oh/Ol (q). MODE 2: kn/v.
// ---------------------------------------------------------------------------
template <int MODE>
__global__ __launch_bounds__(256) void gemm_split(
    const bf* __restrict__ Ah, const bf* __restrict__ Al,
    const bf* __restrict__ Bh, const bf* __restrict__ Bl,
    const float* __restrict__ freqs,
    float* __restrict__ Cf, bf* __restrict__ Oh, bf* __restrict__ Ol,
    bf* __restrict__ O2, int M, int N, int K)
{
    __shared__ bf sAh[128 * 32], sAl[128 * 32];
    __shared__ bf sBh[128 * 32], sBl[128 * 32];

    const int tid = threadIdx.x;
    const int lane = tid & 63, wave = tid >> 6;
    const int row0 = blockIdx.y * 128, col0 = blockIdx.x * 128;
    const int wm = (wave & 1) * 64, wn = (wave >> 1) * 64;
    const int fr = lane & 15, quad = lane >> 4;

    f32x4 acc[4][4];
#pragma unroll
    for (int i = 0; i < 4; i++)
#pragma unroll
        for (int j = 0; j < 4; j++) acc[i][j] = (f32x4){0.f, 0.f, 0.f, 0.f};

    const int trow = tid >> 2;
    const int tcol = (tid & 3) * 8;
    const size_t ldsoff = (size_t)wave * 1024;
    int br0 = col0 + trow;      if (br0 > N - 1) br0 = N - 1;
    int br1 = col0 + 64 + trow; if (br1 > N - 1) br1 = N - 1;

    for (int kt = 0; kt < K; kt += 32) {
        __syncthreads();
        GLOAD_LDS16(Ah + (size_t)(row0 + trow) * K + kt + tcol,      (char*)sAh + ldsoff);
        GLOAD_LDS16(Ah + (size_t)(row0 + 64 + trow) * K + kt + tcol, (char*)sAh + 4096 + ldsoff);
        GLOAD_LDS16(Al + (size_t)(row0 + trow) * K + kt + tcol,      (char*)sAl + ldsoff);
        GLOAD_LDS16(Al + (size_t)(row0 + 64 + trow) * K + kt + tcol, (char*)sAl + 4096 + ldsoff);
        GLOAD_LDS16(Bh + (size_t)br0 * K + kt + tcol, (char*)sBh + ldsoff);
        GLOAD_LDS16(Bh + (size_t)br1 * K + kt + tcol, (char*)sBh + 4096 + ldsoff);
        GLOAD_LDS16(Bl + (size_t)br0 * K + kt + tcol, (char*)sBl + ldsoff);
        GLOAD_LDS16(Bl + (size_t)br1 * K + kt + tcol, (char*)sBl + 4096 + ldsoff);
        __syncthreads();

        bf16x8 a_h[4], a_l[4], b_h[4], b_l[4];
#pragma unroll
        for (int mt = 0; mt < 4; mt++) {
            const int r = (wm + mt * 16 + fr) * 32 + quad * 8;
            a_h[mt] = *(const bf16x8*)&sAh[r];
            a_l[mt] = *(const bf16x8*)&sAl[r];
        }
#pragma unroll
        for (int nt = 0; nt < 4; nt++) {
            const int r = (wn + nt * 16 + fr) * 32 + quad * 8;
            b_h[nt] = *(const bf16x8*)&sBh[r];
            b_l[nt] = *(const bf16x8*)&sBl[r];
        }
#pragma unroll
        for (int mt = 0; mt < 4; mt++)
#pragma unroll
            for (int nt = 0; nt < 4; nt++) {
                acc[mt][nt] = __builtin_amdgcn_mfma_f32_16x16x32_bf16(
                    a_l[mt], b_h[nt], acc[mt][nt], 0, 0, 0);
                acc[mt][nt] = __builtin_amdgcn_mfma_f32_16x16x32_bf16(
                    a_h[mt], b_l[nt], acc[mt][nt], 0, 0, 0);
                acc[mt][nt] = __builtin_amdgcn_mfma_f32_16x16x32_bf16(
                    a_h[mt], b_h[nt], acc[mt][nt], 0, 0, 0);
            }
    }

#pragma unroll
    for (int mt = 0; mt < 4; mt++)
#pragma unroll
        for (int nt = 0; nt < 4; nt++) {
            const int colb = col0 + wn + nt * 16;
            const int col = colb + fr;
            if (MODE == 0) {
#pragma unroll
                for (int r = 0; r < 4; r++) {
                    const int row = row0 + wm + mt * 16 + quad * 4 + r;
                    if (col < N) Cf[(size_t)row * N + col] = acc[mt][nt][r];
                }
            } else if (MODE == 1) {
                const int d0 = colb % 192;
                const bool rope = (d0 >= 128);
                const int ii = (d0 + fr - 128) >> 1;
#pragma unroll
                for (int r = 0; r < 4; r++) {
                    const int row = row0 + wm + mt * 16 + quad * 4 + r;
                    float v = acc[mt][nt][r];
                    if (rope) {
                        const float other = __shfl_xor(v, 1);
                        float sn, cs; sincosf(freqs[row * 32 + ii], &sn, &cs);
                        v = (fr & 1) ? (other * sn + v * cs) : (v * cs - other * sn);
                    }
                    bf h8, l8; split2(v, &h8, &l8);
                    Oh[(size_t)row * N + col] = h8;
                    Ol[(size_t)row * N + col] = l8;
                }
            } else {
                const int hh = col >> 8;
                const int d = col & 255;
#pragma unroll
                for (int r = 0; r < 4; r++) {
                    const int row = row0 + wm + mt * 16 + quad * 4 + r;
                    const float v = acc[mt][nt][r];
                    if (d < 128) {
                        bf h8, l8; split2(v, &h8, &l8);
                        Oh[(size_t)row * 2048 + hh * 128 + d] = h8;
                        Ol[(size_t)row * 2048 + hh * 128 + d] = l8;
                    } else {
                        O2[(size_t)row * 2048 + hh * 128 + (d - 128)] = __float2bfloat16(v);
                    }
                }
            }
        }
}

// ---------------------------------------------------------------------------
// Plain bf16 GEMM (post-softmax out-projection): C = A @ B^T, single MFMA.
// ---------------------------------------------------------------------------
__global__ __launch_bounds__(256) void gemm_bf16(
    const bf* __restrict__ Ah, const bf* __restrict__ Bh,
    float* __restrict__ Cf, int M, int N, int K)
{
    __shared__ bf sAh[128 * 32];
    __shared__ bf sBh[128 * 32];

    const int tid = threadIdx.x;
    const int lane = tid & 63, wave = tid >> 6;
    const int row0 = blockIdx.y * 128, col0 = blockIdx.x * 128;
    const int wm = (wave & 1) * 64, wn = (wave >> 1) * 64;
    const int fr = lane & 15, quad = lane >> 4;

    f32x4 acc[4][4];
#pragma unroll
    for (int i = 0; i < 4; i++)
#pragma unroll
        for (int j = 0; j < 4; j++) acc[i][j] = (f32x4){0.f, 0.f, 0.f, 0.f};

    const int trow = tid >> 2;
    const int tcol = (tid & 3) * 8;
    const size_t ldsoff = (size_t)wave * 1024;

    for (int kt = 0; kt < K; kt += 32) {
        __syncthreads();
        GLOAD_LDS16(Ah + (size_t)(row0 + trow) * K + kt + tcol,      (char*)sAh + ldsoff);
        GLOAD_LDS16(Ah + (size_t)(row0 + 64 + trow) * K + kt + tcol, (char*)sAh + 4096 + ldsoff);
        GLOAD_LDS16(Bh + (size_t)(col0 + trow) * K + kt + tcol,      (char*)sBh + ldsoff);
        GLOAD_LDS16(Bh + (size_t)(col0 + 64 + trow) * K + kt + tcol, (char*)sBh + 4096 + ldsoff);
        __syncthreads();

        bf16x8 a_h[4], b_h[4];
#pragma unroll
        for (int mt = 0; mt < 4; mt++)
            a_h[mt] = *(const bf16x8*)&sAh[(wm + mt * 16 + fr) * 32 + quad * 8];
#pragma unroll
        for (int nt = 0; nt < 4; nt++)
            b_h[nt] = *(const bf16x8*)&sBh[(wn + nt * 16 + fr) * 32 + quad * 8];
#pragma unroll
        for (int mt = 0; mt < 4; mt++)
#pragma unroll
            for (int nt = 0; nt < 4; nt++)
                acc[mt][nt] = __builtin_amdgcn_mfma_f32_16x16x32_bf16(
                    a_h[mt], b_h[nt], acc[mt][nt], 0, 0, 0);
    }

#pragma unroll
    for (int mt = 0; mt < 4; mt++)
#pragma unroll
        for (int nt = 0; nt < 4; nt++)
#pragma unroll
            for (int r = 0; r < 4; r++)
                Cf[(size_t)(row0 + wm + mt * 16 + quad * 4 + r) * N +
                   col0 + wn + nt * 16 + fr] = acc[mt][nt][r];
}

// ---------------------------------------------------------------------------
// Split-K MFMA flash attention. 1280 blocks = 16 heads x 80 (qt, slice).
// Slice = 512 keys (<=4 k-tiles of 128). Partial O (bf16) + m,l (f32) -> ws.
// LDS 35 KB: sQ(h,l) 8K, sK(h,l) 16K (sVt aliases sKh), Ps 64x72 bf16 (9K,
// padded stride = no 16-way conflicts), red 2K. 4 blocks/CU.
// ---------------------------------------------------------------------------
__global__ __launch_bounds__(256, 4) void attn_mfma(
    const bf* __restrict__ qh, const bf* __restrict__ ql,
    const bf* __restrict__ knh, const bf* __restrict__ knl,
    const bf* __restrict__ kpeh, const bf* __restrict__ kpel,
    const bf* __restrict__ vT,
    char* __restrict__ part1, char* __restrict__ part2)
{
    const int bid = blockIdx.x;
    const int h = bid & 15;
    const int sidx = bid >> 4;          // 0..79
    int qt, s;
    if (sidx < 8)       { qt = sidx; s = 0; }
    else if (sidx < 24) { const int r = sidx - 8;  qt = 8  + (r >> 1); s = r & 1; }
    else if (sidx < 48) { const int r = sidx - 24; qt = 16 + r / 3;    s = r % 3; }
    else                { const int r = sidx - 48; qt = 24 + (r >> 2); s = r & 3; }

    const int tid = threadIdx.x;
    const int lane = tid & 63, wave = tid >> 6;
    const int fr = lane & 15, quad = lane >> 4;
    const int wn = wave * 32;

    __shared__ __align__(16) char smem[35840];
    bf* sQh = (bf*)(smem);
    bf* sQl = (bf*)(smem + 4096);
    bf* sKh = (bf*)(smem + 8192);
    bf* sKl = (bf*)(smem + 16384);
    bf* sVt = (bf*)(smem + 8192);         // alias over sKh (dead during PV)
    bf* Ps  = (bf*)(smem + 24576);        // [64][72] padded
    float* redM = (float*)(smem + 33792); // [64][4]
    float* redS = (float*)(smem + 34816); // [64][4]

    float m_i[16], l_i[16], al[16];
    f32x4 O[4][2];
#pragma unroll
    for (int i = 0; i < 16; i++) { m_i[i] = -INFINITY; l_i[i] = 0.0f; }
#pragma unroll
    for (int mt = 0; mt < 4; mt++)
#pragma unroll
        for (int nt = 0; nt < 2; nt++) O[mt][nt] = (f32x4){0.f, 0.f, 0.f, 0.f};

    const int q0 = qt * 64;
    const int kstart = s * 512;
    const int kend = min(kstart + 512, (qt + 1) * 64);
    const int trow = tid >> 2, tcol = (tid & 3) * 8;
    const size_t loff = (size_t)wave * 1024;

    for (int k0 = kstart; k0 < kend; k0 += 128) {
        f32x4 S[4][2];
#pragma unroll
        for (int mt = 0; mt < 4; mt++)
#pragma unroll
            for (int nt = 0; nt < 2; nt++) S[mt][nt] = (f32x4){0.f, 0.f, 0.f, 0.f};

        // ---- S = Q.K^T over 192 dims, 6 chunks of 32 ----
        for (int ch = 0; ch < 6; ch++) {
            const int d0 = ch * 32;
            __syncthreads();
            GLOAD_LDS16(qh + ((size_t)(q0 + trow) * 16 + h) * 192 + d0 + tcol, (char*)sQh + loff);
            GLOAD_LDS16(ql + ((size_t)(q0 + trow) * 16 + h) * 192 + d0 + tcol, (char*)sQl + loff);
            if (d0 < 128) {
                GLOAD_LDS16(knh + ((size_t)(k0 + trow) * 16 + h) * 128 + d0 + tcol,      (char*)sKh + loff);
                GLOAD_LDS16(knh + ((size_t)(k0 + 64 + trow) * 16 + h) * 128 + d0 + tcol, (char*)sKh + 4096 + loff);
                GLOAD_LDS16(knl + ((size_t)(k0 + trow) * 16 + h) * 128 + d0 + tcol,      (char*)sKl + loff);
                GLOAD_LDS16(knl + ((size_t)(k0 + 64 + trow) * 16 + h) * 128 + d0 + tcol, (char*)sKl + 4096 + loff);
            } else {
                GLOAD_LDS16(kpeh + (size_t)(k0 + trow) * 64 + (d0 - 128) + tcol,      (char*)sKh + loff);
                GLOAD_LDS16(kpeh + (size_t)(k0 + 64 + trow) * 64 + (d0 - 128) + tcol, (char*)sKh + 4096 + loff);
                GLOAD_LDS16(kpel + (size_t)(k0 + trow) * 64 + (d0 - 128) + tcol,      (char*)sKl + loff);
                GLOAD_LDS16(kpel + (size_t)(k0 + 64 + trow) * 64 + (d0 - 128) + tcol, (char*)sKl + 4096 + loff);
            }
            __syncthreads();

            bf16x8 a_h[4], a_l[4], b_h[2], b_l[2];
#pragma unroll
            for (int mt = 0; mt < 4; mt++) {
                const int r = (mt * 16 + fr) * 32 + quad * 8;
                a_h[mt] = *(const bf16x8*)&sQh[r];
                a_l[mt] = *(const bf16x8*)&sQl[r];
            }
#pragma unroll
            for (int nt = 0; nt < 2; nt++) {
                const int r = (wn + nt * 16 + fr) * 32 + quad * 8;
                b_h[nt] = *(const bf16x8*)&sKh[r];
                b_l[nt] = *(const bf16x8*)&sKl[r];
            }
#pragma unroll
            for (int mt = 0; mt < 4; mt++)
#pragma unroll
                for (int nt = 0; nt < 2; nt++) {
                    S[mt][nt] = __builtin_amdgcn_mfma_f32_16x16x32_bf16(
                        a_l[mt], b_h[nt], S[mt][nt], 0, 0, 0);
                    S[mt][nt] = __builtin_amdgcn_mfma_f32_16x16x32_bf16(
                        a_h[mt], b_l[nt], S[mt][nt], 0, 0, 0);
                    S[mt][nt] = __builtin_amdgcn_mfma_f32_16x16x32_bf16(
                        a_h[mt], b_h[nt], S[mt][nt], 0, 0, 0);
                }
        }

        // ---- online softmax (fp32, block-wide row reductions) ----
#pragma unroll
        for (int mt = 0; mt < 4; mt++)
#pragma unroll
            for (int rr = 0; rr < 4; rr++) {
                const int ri = mt * 16 + quad * 4 + rr;
                const int rowg = q0 + ri;
                float v0 = S[mt][0][rr] * SOFTSCALE;
                float v1 = S[mt][1][rr] * SOFTSCALE;
                if (k0 + wn + fr > rowg)      v0 = -INFINITY;
                if (k0 + wn + 16 + fr > rowg) v1 = -INFINITY;
                S[mt][0][rr] = v0; S[mt][1][rr] = v1;
                float pm = fmaxf(v0, v1);
#pragma unroll
                for (int o = 1; o < 16; o <<= 1) pm = fmaxf(pm, __shfl_xor(pm, o, 64));
                if (fr == 0) redM[ri * 4 + wave] = pm;
            }
        __syncthreads();
#pragma unroll
        for (int mt = 0; mt < 4; mt++)
#pragma unroll
            for (int rr = 0; rr < 4; rr++) {
                const int idx = mt * 4 + rr;
                const int ri = mt * 16 + quad * 4 + rr;
                const float4 g = *(const float4*)&redM[ri * 4];
                const float gm = fmaxf(fmaxf(g.x, g.y), fmaxf(g.z, g.w));
                const float mn = fmaxf(m_i[idx], gm);
                al[idx] = __expf(m_i[idx] - mn);
                m_i[idx] = mn;
                const float p0 = __expf(S[mt][0][rr] - mn);
                const float p1 = __expf(S[mt][1][rr] - mn);
                float ps = p0 + p1;
#pragma unroll
                for (int o = 1; o < 16; o <<= 1) ps += __shfl_xor(ps, o, 64);
                if (fr == 0) redS[ri * 4 + wave] = ps;
            }
#pragma unroll
        for (int mt = 0; mt < 4; mt++)
#pragma unroll
            for (int nt = 0; nt < 2; nt++)
#pragma unroll
                for (int rr = 0; rr < 4; rr++) O[mt][nt][rr] *= al[mt * 4 + rr];
        __syncthreads();
#pragma unroll
        for (int mt = 0; mt < 4; mt++)
#pragma unroll
            for (int rr = 0; rr < 4; rr++) {
                const int idx = mt * 4 + rr;
                const int ri = mt * 16 + quad * 4 + rr;
                const float4 s4 = *(const float4*)&redS[ri * 4];
                l_i[idx] = l_i[idx] * al[idx] + (s4.x + s4.y + s4.z + s4.w);
            }

        // ---- PV in two 64-key halves (Ps 64x72 bf16, padded) ----
#pragma unroll
        for (int half = 0; half < 2; half++) {
            if ((wave >> 1) == half) {
                const int kc = wn - half * 64;   // 0 or 32
#pragma unroll
                for (int mt = 0; mt < 4; mt++)
#pragma unroll
                    for (int rr = 0; rr < 4; rr++) {
                        const int idx = mt * 4 + rr;
                        const int ri = mt * 16 + quad * 4 + rr;
                        Ps[ri * 72 + kc + fr]      = __float2bfloat16(__expf(S[mt][0][rr] - m_i[idx]));
                        Ps[ri * 72 + kc + 16 + fr] = __float2bfloat16(__expf(S[mt][1][rr] - m_i[idx]));
                    }
            }
#pragma unroll
            for (int vc = 0; vc < 2; vc++) {
                const int kb = k0 + half * 64 + vc * 32;
                GLOAD_LDS16(vT + ((size_t)(h * 128 + trow)) * 2048 + kb + tcol,      (char*)sVt + loff);
                GLOAD_LDS16(vT + ((size_t)(h * 128 + 64 + trow)) * 2048 + kb + tcol, (char*)sVt + 4096 + loff);
                __syncthreads();
                bf16x8 ap[4], bv[2];
#pragma unroll
                for (int mt = 0; mt < 4; mt++)
                    ap[mt] = *(const bf16x8*)&Ps[(mt * 16 + fr) * 72 + vc * 32 + quad * 8];
#pragma unroll
                for (int nt = 0; nt < 2; nt++)
                    bv[nt] = *(const bf16x8*)&sVt[(wn + nt * 16 + fr) * 32 + quad * 8];
#pragma unroll
                for (int mt = 0; mt < 4; mt++)
#pragma unroll
                    for (int nt = 0; nt < 2; nt++)
                        O[mt][nt] = __builtin_amdgcn_mfma_f32_16x16x32_bf16(
                            ap[mt], bv[nt], O[mt][nt], 0, 0, 0);
                __syncthreads();
            }
        }
    }

    // ---- partial store: O bf16, m, l ----
    const int g = h * 80 + sidx;
    char* base = (g < PART1_CAP) ? part1 + (size_t)g * SLICE_BYTES
                                 : part2 + (size_t)(g - PART1_CAP) * SLICE_BYTES;
    bf* Op = (bf*)base;
    float* mp = (float*)(base + 16384);
    float* lp = (float*)(base + 16640);
#pragma unroll
    for (int mt = 0; mt < 4; mt++)
#pragma unroll
        for (int rr = 0; rr < 4; rr++) {
            const int idx = mt * 4 + rr;
            const int ri = mt * 16 + quad * 4 + rr;
#pragma unroll
            for (int nt = 0; nt < 2; nt++)
                Op[ri * 128 + wn + nt * 16 + fr] = __float2bfloat16(O[mt][nt][rr]);
            if (wave == 0 && fr == 0) { mp[ri] = m_i[idx]; lp[ri] = l_i[idx]; }
        }
}

// ---------------------------------------------------------------------------
// Merge split-K partials: y[row,h,:] = sum_s w_s * O_s / sum_s w_s l_s.
// Grid 512 = 16 heads x 32 q-tiles.
// ---------------------------------------------------------------------------
__global__ __launch_bounds__(256) void attn_merge(
    const char* __restrict__ part1, const char* __restrict__ part2,
    bf* __restrict__ yh)
{
    const int h = blockIdx.x & 15, qt = blockIdx.x >> 4;
    const int a = qt >> 3, b = qt & 7;
    const int sidx0 = 4 * a * (a + 1) + b * (a + 1);
    const int nst = a + 1;
    const int tid = threadIdx.x;
    const int r = tid >> 2;
    const int c0 = (tid & 3) * 32;

    const char* bases[4];
    float m_s[4], l_s[4];
    for (int s = 0; s < nst; s++) {
        const int g = h * 80 + sidx0 + s;
        bases[s] = (g < PART1_CAP) ? part1 + (size_t)g * SLICE_BYTES
                                   : part2 + (size_t)(g - PART1_CAP) * SLICE_BYTES;
        m_s[s] = ((const float*)(bases[s] + 16384))[r];
        l_s[s] = ((const float*)(bases[s] + 16640))[r];
    }
    float M = -INFINITY;
    for (int s = 0; s < nst; s++) M = fmaxf(M, m_s[s]);
    float denom = 0.0f;
    for (int s = 0; s < nst; s++) denom += __expf(m_s[s] - M) * l_s[s];
    float w[4];
    for (int s = 0; s < nst; s++) w[s] = __expf(m_s[s] - M) / denom;

    const int row = qt * 64 + r;
    bf* dst = yh + ((size_t)row * 16 + h) * 128 + c0;
#pragma unroll
    for (int cc = 0; cc < 32; cc += 8) {
        float acc[8] = {0, 0, 0, 0, 0, 0, 0, 0};
        for (int s = 0; s < nst; s++) {
            const bf16x8 ov = *(const bf16x8*)((const bf*)bases[s] + r * 128 + c0 + cc);
#pragma unroll
            for (int u = 0; u < 8; u++) {
                union { short s16; bf b16; } cv; cv.s16 = ov[u];
                acc[u] += w[s] * __bfloat162float(cv.b16);
            }
        }
#pragma unroll
        for (int u = 0; u < 8; u++) dst[cc + u] = __float2bfloat16(acc[u]);
    }
}

// ---------------------------------------------------------------------------
// Workspace (peak 84.4 MB, <= 86.6 MB proven):
//  A  @0        : xh(8.39) xl(8.39) -> yh(8.39)@0, vT(8.39)@8.39
//  AR @16.78    : (16.78) GEMM temporaries -> attn partials region1 -> woh
//  persistent   : qh@33.55 ql@46.14 knh@58.72 knl@67.11 vh@75.50(->partials
//                 region2) kpeh@83.89 kpel@84.15
// ---------------------------------------------------------------------------
extern "C" void kernel_launch(void* const* d_in, const int* in_sizes, int n_in,
                              void* d_out, int out_size, void* d_ws, size_t ws_size,
                              hipStream_t stream)
{
    const float* x        = (const float*)d_in[0];
    const float* freqs    = (const float*)d_in[1];
    const float* wq_a     = (const float*)d_in[3];
    const float* q_norm_w = (const float*)d_in[4];
    const float* wq_b     = (const float*)d_in[5];
    const float* wkv_a    = (const float*)d_in[6];
    const float* kv_norm_w= (const float*)d_in[7];
    const float* wkv_b    = (const float*)d_in[8];
    const float* wo       = (const float*)d_in[9];
    float* out            = (float*)d_out;

    char* ws = (char*)d_ws;
    bf* xh = (bf*)(ws);
    bf* xl = (bf*)(ws + 8388608);
    bf* yh = (bf*)(ws);                   // after x dead
    bf* vT = (bf*)(ws + 8388608);         // after x dead
    char* AR = ws + 16777216;
    bf*    wah    = (bf*)(AR);
    bf*    wal    = (bf*)(AR + 3145728);
    float* qa     = (float*)(AR + 6291456);
    bf*    qah    = (bf*)(AR);
    bf*    qal    = (bf*)(AR + 3145728);
    bf*    wbh    = (bf*)(AR + 6291456);
    bf*    wbl    = (bf*)(AR + 11010048);
    bf*    kah    = (bf*)(AR);
    bf*    kal    = (bf*)(AR + 2359296);
    float* kvfull = (float*)(AR + 4718592);
    bf*    ckvh   = (bf*)(AR + 9437184);
    bf*    ckvl   = (bf*)(AR + 11534336);
    bf*    wvh    = (bf*)(AR);
    bf*    wvl    = (bf*)(AR + 4194304);
    char*  part1  = AR;                   // during attention
    bf*    woh    = (bf*)(AR);            // after merge
    bf* qh   = (bf*)(ws + 33554432);
    bf* ql   = (bf*)(ws + 46137344);
    bf* knh  = (bf*)(ws + 58720256);
    bf* knl  = (bf*)(ws + 67108864);
    bf* vh   = (bf*)(ws + 75497472);
    char* part2 = ws + 75497472;          // vh dead after transpose
    bf* kpeh = (bf*)(ws + 83886080);
    bf* kpel = (bf*)(ws + 84148224);

    dim3 blk(256);

    cvt_split<<<4096, blk, 0, stream>>>(x, xh, xl, D_MODEL * D_MODEL);
    cvt_split<<<1536, blk, 0, stream>>>(wq_a, wah, wal, QLORA * D_MODEL);
    gemm_split<0><<<dim3(6, 16), blk, 0, stream>>>(
        xh, xl, wah, wal, nullptr, qa, nullptr, nullptr, nullptr,
        T_DIM, QLORA, D_MODEL);
    rmsnorm_cvt<<<T_DIM, blk, 0, stream>>>(qa, QLORA, QLORA, q_norm_w, qah, qal);
    cvt_split<<<2304, blk, 0, stream>>>(wq_b, wbh, wbl, 3072 * QLORA);
    gemm_split<1><<<dim3(24, 16), blk, 0, stream>>>(
        qah, qal, wbh, wbl, freqs, nullptr, qh, ql, nullptr,
        T_DIM, 3072, QLORA);
    cvt_split<<<1152, blk, 0, stream>>>(wkv_a, kah, kal, KVFULL_D * D_MODEL);
    gemm_split<0><<<dim3(5, 16), blk, 0, stream>>>(
        xh, xl, kah, kal, nullptr, kvfull, nullptr, nullptr, nullptr,
        T_DIM, KVFULL_D, D_MODEL);
    rope_k_cvt<<<256, blk, 0, stream>>>(kvfull, freqs, kpeh, kpel);
    rmsnorm_cvt<<<T_DIM, blk, 0, stream>>>(kvfull, KVFULL_D, KVLORA, kv_norm_w, ckvh, ckvl);
    cvt_split<<<2048, blk, 0, stream>>>(wkv_b, wvh, wvl, 4096 * KVLORA);
    gemm_split<2><<<dim3(32, 16), blk, 0, stream>>>(
        ckvh, ckvl, wvh, wvl, nullptr, nullptr, knh, knl, vh,
        T_DIM, 4096, KVLORA);
    transpose_v<<<dim3(64, 4, 16), blk, 0, stream>>>(vh, vT);
    attn_mfma<<<dim3(1280), blk, 0, stream>>>(
        qh, ql, knh, knl, kpeh, kpel, vT, part1, part2);
    attn_merge<<<dim3(512), blk, 0, stream>>>(part1, part2, yh);
    cvt_hi<<<4096, blk, 0, stream>>>(wo, woh, D_MODEL * D_MODEL);
    gemm_bf16<<<dim3(16, 16), blk, 0, stream>>>(
        yh, woh, out, T_DIM, D_MODEL, D_MODEL);
}

// Round 7
// 801.510 us; speedup vs baseline: 1.4470x; 1.4470x over previous
//
#include <hip/hip_runtime.h>
#include <hip/hip_bf16.h>
#include <math.h>

// ---------------------------------------------------------------------------
// DeepSeek MLA forward. Round 7 = Round 6 structure with the spill fixed:
//  - attn_mfma __launch_bounds__(256,2): R6's (256,4) forced a 128 unified
//    VGPR+AGPR cap -> 64 arch VGPRs -> 1.4 GB scratch spill traffic (the
//    whole regression). (256,2) reproduces R5's 128-VGPR allocation.
//  - Split-K flash-decoding attention (1280 blocks, <=4 k-tiles each),
//    padded Ps (stride 72) -> no 16-way conflicts, partials + merge.
//  - Score path split-bf16 3-MFMA; post-softmax path plain bf16 MFMA.
// ---------------------------------------------------------------------------

#define T_DIM 2048
#define HEADS 16
#define D_MODEL 2048
#define NOPE_D 128
#define ROPE_D 64
#define QKD_D 192
#define VD_D 128
#define QLORA 768
#define KVLORA 512
#define KVFULL_D 576
#define SOFTSCALE -96.0f
#define EPS_RMS 1e-6f

typedef __hip_bfloat16 bf;
typedef __attribute__((ext_vector_type(8))) short bf16x8;
typedef __attribute__((ext_vector_type(4))) float f32x4;

#define SLICE_BYTES 16896   // O 64x128 bf16 (16384) + m 64 f32 + l 64 f32
#define PART1_CAP 992       // slices in 16.78 MB arena

#define GLOAD_LDS16(gptr, lptr)                                               \
    __builtin_amdgcn_global_load_lds(                                         \
        (const __attribute__((address_space(1))) unsigned int*)(gptr),        \
        (__attribute__((address_space(3))) unsigned int*)(lptr), 16, 0, 0)

__device__ __forceinline__ void split2(float v, bf* hi, bf* lo) {
    bf h = __float2bfloat16(v);
    *hi = h;
    *lo = __float2bfloat16(v - __bfloat162float(h));
}

// ---------------------------------------------------------------------------
__global__ __launch_bounds__(256) void cvt_split(
    const float* __restrict__ in, bf* __restrict__ hi, bf* __restrict__ lo, int n)
{
    const int i = (blockIdx.x * 256 + threadIdx.x) * 4;
    if (i >= n) return;
    float4 v = *(const float4*)&in[i];
    float vv[4] = {v.x, v.y, v.z, v.w};
#pragma unroll
    for (int u = 0; u < 4; u++) split2(vv[u], &hi[i + u], &lo[i + u]);
}

__global__ __launch_bounds__(256) void cvt_hi(
    const float* __restrict__ in, bf* __restrict__ hi, int n)
{
    const int i = (blockIdx.x * 256 + threadIdx.x) * 4;
    if (i >= n) return;
    float4 v = *(const float4*)&in[i];
    hi[i + 0] = __float2bfloat16(v.x);
    hi[i + 1] = __float2bfloat16(v.y);
    hi[i + 2] = __float2bfloat16(v.z);
    hi[i + 3] = __float2bfloat16(v.w);
}

// ---------------------------------------------------------------------------
__global__ __launch_bounds__(256) void rmsnorm_cvt(
    const float* __restrict__ in, int ld, int D, const float* __restrict__ w,
    bf* __restrict__ hi, bf* __restrict__ lo)
{
    const int row = blockIdx.x;
    const float* r = in + (size_t)row * ld;
    float ss = 0.0f;
    for (int i = threadIdx.x; i < D; i += 256) { float v = r[i]; ss += v * v; }
#pragma unroll
    for (int o = 32; o > 0; o >>= 1) ss += __shfl_down(ss, o, 64);
    __shared__ float red[4];
    if ((threadIdx.x & 63) == 0) red[threadIdx.x >> 6] = ss;
    __syncthreads();
    ss = red[0] + red[1] + red[2] + red[3];
    const float scale = rsqrtf(ss / (float)D + EPS_RMS);
    for (int i = threadIdx.x; i < D; i += 256) {
        const float v = r[i] * scale * w[i];
        split2(v, &hi[(size_t)row * D + i], &lo[(size_t)row * D + i]);
    }
}

// ---------------------------------------------------------------------------
__global__ __launch_bounds__(256) void rope_k_cvt(
    const float* __restrict__ kvfull, const float* __restrict__ freqs,
    bf* __restrict__ kpeh, bf* __restrict__ kpel)
{
    const int idx = blockIdx.x * 256 + threadIdx.x;   // 65536
    const int i = idx & 31, t = idx >> 5;
    const float f = freqs[t * 32 + i];
    float sn, cs; sincosf(f, &sn, &cs);
    const float x1 = kvfull[(size_t)t * KVFULL_D + KVLORA + 2 * i];
    const float x2 = kvfull[(size_t)t * KVFULL_D + KVLORA + 2 * i + 1];
    split2(x1 * cs - x2 * sn, &kpeh[t * 64 + 2 * i], &kpel[t * 64 + 2 * i]);
    split2(x1 * sn + x2 * cs, &kpeh[t * 64 + 2 * i + 1], &kpel[t * 64 + 2 * i + 1]);
}

// ---------------------------------------------------------------------------
__global__ __launch_bounds__(256) void transpose_v(
    const bf* __restrict__ vh, bf* __restrict__ vT)
{
    __shared__ bf s[32][33];
    const int t0 = blockIdx.x * 32, d0 = blockIdx.y * 32, h = blockIdx.z;
    const int tid = threadIdx.x;
    const int i = tid >> 3, j0 = (tid & 7) * 4;
    const bf* src = vh + ((size_t)(t0 + i) * 16 + h) * 128 + d0 + j0;
#pragma unroll
    for (int u = 0; u < 4; u++) s[i][j0 + u] = src[u];
    __syncthreads();
    const int jj = tid >> 3, i0 = (tid & 7) * 4;
    bf* dst = vT + ((size_t)h * 128 + d0 + jj) * 2048 + t0 + i0;
#pragma unroll
    for (int u = 0; u < 4; u++) dst[u] = s[i0 + u][jj];
}

// ---------------------------------------------------------------------------
// Split-bf16 GEMM (score path), 128x128 tile, 3 MFMAs. MODE 0: C fp32
// (+N guard). MODE 1: RoPE on d>=128 + split -> Oh/Ol (q). MODE 2: kn/v.
// ---------------------------------------------------------------------------
template <int MODE>
__global__ __launch_bounds__(256) void gemm_split(
    const bf* __restrict__ Ah, const bf* __restrict__ Al,
    const bf* __restrict__ Bh, const bf* __restrict__ Bl,
    const float* __restrict__ freqs,
    float* __restrict__ Cf, bf* __restrict__ Oh, bf* __restrict__ Ol,
    bf* __restrict__ O2, int M, int N, int K)
{
    __shared__ bf sAh[128 * 32], sAl[128 * 32];
    __shared__ bf sBh[128 * 32], sBl[128 * 32];

    const int tid = threadIdx.x;
    const int lane = tid & 63, wave = tid >> 6;
    const int row0 = blockIdx.y * 128, col0 = blockIdx.x * 128;
    const int wm = (wave & 1) * 64, wn = (wave >> 1) * 64;
    const int fr = lane & 15, quad = lane >> 4;

    f32x4 acc[4][4];
#pragma unroll
    for (int i = 0; i < 4; i++)
#pragma unroll
        for (int j = 0; j < 4; j++) acc[i][j] = (f32x4){0.f, 0.f, 0.f, 0.f};

    const int trow = tid >> 2;
    const int tcol = (tid & 3) * 8;
    const size_t ldsoff = (size_t)wave * 1024;
    int br0 = col0 + trow;      if (br0 > N - 1) br0 = N - 1;
    int br1 = col0 + 64 + trow; if (br1 > N - 1) br1 = N - 1;

    for (int kt = 0; kt < K; kt += 32) {
        __syncthreads();
        GLOAD_LDS16(Ah + (size_t)(row0 + trow) * K + kt + tcol,      (char*)sAh + ldsoff);
        GLOAD_LDS16(Ah + (size_t)(row0 + 64 + trow) * K + kt + tcol, (char*)sAh + 4096 + ldsoff);
        GLOAD_LDS16(Al + (size_t)(row0 + trow) * K + kt + tcol,      (char*)sAl + ldsoff);
        GLOAD_LDS16(Al + (size_t)(row0 + 64 + trow) * K + kt + tcol, (char*)sAl + 4096 + ldsoff);
        GLOAD_LDS16(Bh + (size_t)br0 * K + kt + tcol, (char*)sBh + ldsoff);
        GLOAD_LDS16(Bh + (size_t)br1 * K + kt + tcol, (char*)sBh + 4096 + ldsoff);
        GLOAD_LDS16(Bl + (size_t)br0 * K + kt + tcol, (char*)sBl + ldsoff);
        GLOAD_LDS16(Bl + (size_t)br1 * K + kt + tcol, (char*)sBl + 4096 + ldsoff);
        __syncthreads();

        bf16x8 a_h[4], a_l[4], b_h[4], b_l[4];
#pragma unroll
        for (int mt = 0; mt < 4; mt++) {
            const int r = (wm + mt * 16 + fr) * 32 + quad * 8;
            a_h[mt] = *(const bf16x8*)&sAh[r];
            a_l[mt] = *(const bf16x8*)&sAl[r];
        }
#pragma unroll
        for (int nt = 0; nt < 4; nt++) {
            const int r = (wn + nt * 16 + fr) * 32 + quad * 8;
            b_h[nt] = *(const bf16x8*)&sBh[r];
            b_l[nt] = *(const bf16x8*)&sBl[r];
        }
#pragma unroll
        for (int mt = 0; mt < 4; mt++)
#pragma unroll
            for (int nt = 0; nt < 4; nt++) {
                acc[mt][nt] = __builtin_amdgcn_mfma_f32_16x16x32_bf16(
                    a_l[mt], b_h[nt], acc[mt][nt], 0, 0, 0);
                acc[mt][nt] = __builtin_amdgcn_mfma_f32_16x16x32_bf16(
                    a_h[mt], b_l[nt], acc[mt][nt], 0, 0, 0);
                acc[mt][nt] = __builtin_amdgcn_mfma_f32_16x16x32_bf16(
                    a_h[mt], b_h[nt], acc[mt][nt], 0, 0, 0);
            }
    }

#pragma unroll
    for (int mt = 0; mt < 4; mt++)
#pragma unroll
        for (int nt = 0; nt < 4; nt++) {
            const int colb = col0 + wn + nt * 16;
            const int col = colb + fr;
            if (MODE == 0) {
#pragma unroll
                for (int r = 0; r < 4; r++) {
                    const int row = row0 + wm + mt * 16 + quad * 4 + r;
                    if (col < N) Cf[(size_t)row * N + col] = acc[mt][nt][r];
                }
            } else if (MODE == 1) {
                const int d0 = colb % 192;
                const bool rope = (d0 >= 128);
                const int ii = (d0 + fr - 128) >> 1;
#pragma unroll
                for (int r = 0; r < 4; r++) {
                    const int row = row0 + wm + mt * 16 + quad * 4 + r;
                    float v = acc[mt][nt][r];
                    if (rope) {
                        const float other = __shfl_xor(v, 1);
                        float sn, cs; sincosf(freqs[row * 32 + ii], &sn, &cs);
                        v = (fr & 1) ? (other * sn + v * cs) : (v * cs - other * sn);
                    }
                    bf h8, l8; split2(v, &h8, &l8);
                    Oh[(size_t)row * N + col] = h8;
                    Ol[(size_t)row * N + col] = l8;
                }
            } else {
                const int hh = col >> 8;
                const int d = col & 255;
#pragma unroll
                for (int r = 0; r < 4; r++) {
                    const int row = row0 + wm + mt * 16 + quad * 4 + r;
                    const float v = acc[mt][nt][r];
                    if (d < 128) {
                        bf h8, l8; split2(v, &h8, &l8);
                        Oh[(size_t)row * 2048 + hh * 128 + d] = h8;
                        Ol[(size_t)row * 2048 + hh * 128 + d] = l8;
                    } else {
                        O2[(size_t)row * 2048 + hh * 128 + (d - 128)] = __float2bfloat16(v);
                    }
                }
            }
        }
}

// ---------------------------------------------------------------------------
// Plain bf16 GEMM (post-softmax out-projection): C = A @ B^T, single MFMA.
// ---------------------------------------------------------------------------
__global__ __launch_bounds__(256) void gemm_bf16(
    const bf* __restrict__ Ah, const bf* __restrict__ Bh,
    float* __restrict__ Cf, int M, int N, int K)
{
    __shared__ bf sAh[128 * 32];
    __shared__ bf sBh[128 * 32];

    const int tid = threadIdx.x;
    const int lane = tid & 63, wave = tid >> 6;
    const int row0 = blockIdx.y * 128, col0 = blockIdx.x * 128;
    const int wm = (wave & 1) * 64, wn = (wave >> 1) * 64;
    const int fr = lane & 15, quad = lane >> 4;

    f32x4 acc[4][4];
#pragma unroll
    for (int i = 0; i < 4; i++)
#pragma unroll
        for (int j = 0; j < 4; j++) acc[i][j] = (f32x4){0.f, 0.f, 0.f, 0.f};

    const int trow = tid >> 2;
    const int tcol = (tid & 3) * 8;
    const size_t ldsoff = (size_t)wave * 1024;

    for (int kt = 0; kt < K; kt += 32) {
        __syncthreads();
        GLOAD_LDS16(Ah + (size_t)(row0 + trow) * K + kt + tcol,      (char*)sAh + ldsoff);
        GLOAD_LDS16(Ah + (size_t)(row0 + 64 + trow) * K + kt + tcol, (char*)sAh + 4096 + ldsoff);
        GLOAD_LDS16(Bh + (size_t)(col0 + trow) * K + kt + tcol,      (char*)sBh + ldsoff);
        GLOAD_LDS16(Bh + (size_t)(col0 + 64 + trow) * K + kt + tcol, (char*)sBh + 4096 + ldsoff);
        __syncthreads();

        bf16x8 a_h[4], b_h[4];
#pragma unroll
        for (int mt = 0; mt < 4; mt++)
            a_h[mt] = *(const bf16x8*)&sAh[(wm + mt * 16 + fr) * 32 + quad * 8];
#pragma unroll
        for (int nt = 0; nt < 4; nt++)
            b_h[nt] = *(const bf16x8*)&sBh[(wn + nt * 16 + fr) * 32 + quad * 8];
#pragma unroll
        for (int mt = 0; mt < 4; mt++)
#pragma unroll
            for (int nt = 0; nt < 4; nt++)
                acc[mt][nt] = __builtin_amdgcn_mfma_f32_16x16x32_bf16(
                    a_h[mt], b_h[nt], acc[mt][nt], 0, 0, 0);
    }

#pragma unroll
    for (int mt = 0; mt < 4; mt++)
#pragma unroll
        for (int nt = 0; nt < 4; nt++)
#pragma unroll
            for (int r = 0; r < 4; r++)
                Cf[(size_t)(row0 + wm + mt * 16 + quad * 4 + r) * N +
                   col0 + wn + nt * 16 + fr] = acc[mt][nt][r];
}

// ---------------------------------------------------------------------------
// Split-K MFMA flash attention. 1280 blocks = 16 heads x 80 (qt, slice).
// Slice = 512 keys (<=4 k-tiles of 128). Partial O (bf16) + m,l (f32) -> ws.
// LDS 35 KB; Ps padded stride 72. __launch_bounds__(256,2): R6's (256,4)
// capped unified VGPR+AGPR at 128 -> 64 arch VGPRs -> scratch spill (1.4 GB
// traffic). Do NOT raise the min-waves bound on this kernel.
// ---------------------------------------------------------------------------
__global__ __launch_bounds__(256, 2) void attn_mfma(
    const bf* __restrict__ qh, const bf* __restrict__ ql,
    const bf* __restrict__ knh, const bf* __restrict__ knl,
    const bf* __restrict__ kpeh, const bf* __restrict__ kpel,
    const bf* __restrict__ vT,
    char* __restrict__ part1, char* __restrict__ part2)
{
    const int bid = blockIdx.x;
    const int h = bid & 15;
    const int sidx = bid >> 4;          // 0..79
    int qt, s;
    if (sidx < 8)       { qt = sidx; s = 0; }
    else if (sidx < 24) { const int r = sidx - 8;  qt = 8  + (r >> 1); s = r & 1; }
    else if (sidx < 48) { const int r = sidx - 24; qt = 16 + r / 3;    s = r % 3; }
    else                { const int r = sidx - 48; qt = 24 + (r >> 2); s = r & 3; }

    const int tid = threadIdx.x;
    const int lane = tid & 63, wave = tid >> 6;
    const int fr = lane & 15, quad = lane >> 4;
    const int wn = wave * 32;

    __shared__ __align__(16) char smem[35840];
    bf* sQh = (bf*)(smem);
    bf* sQl = (bf*)(smem + 4096);
    bf* sKh = (bf*)(smem + 8192);
    bf* sKl = (bf*)(smem + 16384);
    bf* sVt = (bf*)(smem + 8192);         // alias over sKh (dead during PV)
    bf* Ps  = (bf*)(smem + 24576);        // [64][72] padded
    float* redM = (float*)(smem + 33792); // [64][4]
    float* redS = (float*)(smem + 34816); // [64][4]

    float m_i[16], l_i[16], al[16];
    f32x4 O[4][2];
#pragma unroll
    for (int i = 0; i < 16; i++) { m_i[i] = -INFINITY; l_i[i] = 0.0f; }
#pragma unroll
    for (int mt = 0; mt < 4; mt++)
#pragma unroll
        for (int nt = 0; nt < 2; nt++) O[mt][nt] = (f32x4){0.f, 0.f, 0.f, 0.f};

    const int q0 = qt * 64;
    const int kstart = s * 512;
    const int kend = min(kstart + 512, (qt + 1) * 64);
    const int trow = tid >> 2, tcol = (tid & 3) * 8;
    const size_t loff = (size_t)wave * 1024;

    for (int k0 = kstart; k0 < kend; k0 += 128) {
        f32x4 S[4][2];
#pragma unroll
        for (int mt = 0; mt < 4; mt++)
#pragma unroll
            for (int nt = 0; nt < 2; nt++) S[mt][nt] = (f32x4){0.f, 0.f, 0.f, 0.f};

        // ---- S = Q.K^T over 192 dims, 6 chunks of 32 ----
        for (int ch = 0; ch < 6; ch++) {
            const int d0 = ch * 32;
            __syncthreads();
            GLOAD_LDS16(qh + ((size_t)(q0 + trow) * 16 + h) * 192 + d0 + tcol, (char*)sQh + loff);
            GLOAD_LDS16(ql + ((size_t)(q0 + trow) * 16 + h) * 192 + d0 + tcol, (char*)sQl + loff);
            if (d0 < 128) {
                GLOAD_LDS16(knh + ((size_t)(k0 + trow) * 16 + h) * 128 + d0 + tcol,      (char*)sKh + loff);
                GLOAD_LDS16(knh + ((size_t)(k0 + 64 + trow) * 16 + h) * 128 + d0 + tcol, (char*)sKh + 4096 + loff);
                GLOAD_LDS16(knl + ((size_t)(k0 + trow) * 16 + h) * 128 + d0 + tcol,      (char*)sKl + loff);
                GLOAD_LDS16(knl + ((size_t)(k0 + 64 + trow) * 16 + h) * 128 + d0 + tcol, (char*)sKl + 4096 + loff);
            } else {
                GLOAD_LDS16(kpeh + (size_t)(k0 + trow) * 64 + (d0 - 128) + tcol,      (char*)sKh + loff);
                GLOAD_LDS16(kpeh + (size_t)(k0 + 64 + trow) * 64 + (d0 - 128) + tcol, (char*)sKh + 4096 + loff);
                GLOAD_LDS16(kpel + (size_t)(k0 + trow) * 64 + (d0 - 128) + tcol,      (char*)sKl + loff);
                GLOAD_LDS16(kpel + (size_t)(k0 + 64 + trow) * 64 + (d0 - 128) + tcol, (char*)sKl + 4096 + loff);
            }
            __syncthreads();

            bf16x8 a_h[4], a_l[4], b_h[2], b_l[2];
#pragma unroll
            for (int mt = 0; mt < 4; mt++) {
                const int r = (mt * 16 + fr) * 32 + quad * 8;
                a_h[mt] = *(const bf16x8*)&sQh[r];
                a_l[mt] = *(const bf16x8*)&sQl[r];
            }
#pragma unroll
            for (int nt = 0; nt < 2; nt++) {
                const int r = (wn + nt * 16 + fr) * 32 + quad * 8;
                b_h[nt] = *(const bf16x8*)&sKh[r];
                b_l[nt] = *(const bf16x8*)&sKl[r];
            }
#pragma unroll
            for (int mt = 0; mt < 4; mt++)
#pragma unroll
                for (int nt = 0; nt < 2; nt++) {
                    S[mt][nt] = __builtin_amdgcn_mfma_f32_16x16x32_bf16(
                        a_l[mt], b_h[nt], S[mt][nt], 0, 0, 0);
                    S[mt][nt] = __builtin_amdgcn_mfma_f32_16x16x32_bf16(
                        a_h[mt], b_l[nt], S[mt][nt], 0, 0, 0);
                    S[mt][nt] = __builtin_amdgcn_mfma_f32_16x16x32_bf16(
                        a_h[mt], b_h[nt], S[mt][nt], 0, 0, 0);
                }
        }

        // ---- online softmax (fp32, block-wide row reductions) ----
#pragma unroll
        for (int mt = 0; mt < 4; mt++)
#pragma unroll
            for (int rr = 0; rr < 4; rr++) {
                const int ri = mt * 16 + quad * 4 + rr;
                const int rowg = q0 + ri;
                float v0 = S[mt][0][rr] * SOFTSCALE;
                float v1 = S[mt][1][rr] * SOFTSCALE;
                if (k0 + wn + fr > rowg)      v0 = -INFINITY;
                if (k0 + wn + 16 + fr > rowg) v1 = -INFINITY;
                S[mt][0][rr] = v0; S[mt][1][rr] = v1;
                float pm = fmaxf(v0, v1);
#pragma unroll
                for (int o = 1; o < 16; o <<= 1) pm = fmaxf(pm, __shfl_xor(pm, o, 64));
                if (fr == 0) redM[ri * 4 + wave] = pm;
            }
        __syncthreads();
#pragma unroll
        for (int mt = 0; mt < 4; mt++)
#pragma unroll
            for (int rr = 0; rr < 4; rr++) {
                const int idx = mt * 4 + rr;
                const int ri = mt * 16 + quad * 4 + rr;
                const float4 g = *(const float4*)&redM[ri * 4];
                const float gm = fmaxf(fmaxf(g.x, g.y), fmaxf(g.z, g.w));
                const float mn = fmaxf(m_i[idx], gm);
                al[idx] = __expf(m_i[idx] - mn);
                m_i[idx] = mn;
                const float p0 = __expf(S[mt][0][rr] - mn);
                const float p1 = __expf(S[mt][1][rr] - mn);
                S[mt][0][rr] = p0; S[mt][1][rr] = p1;   // keep p for PV store
                float ps = p0 + p1;
#pragma unroll
                for (int o = 1; o < 16; o <<= 1) ps += __shfl_xor(ps, o, 64);
                if (fr == 0) redS[ri * 4 + wave] = ps;
            }
#pragma unroll
        for (int mt = 0; mt < 4; mt++)
#pragma unroll
            for (int nt = 0; nt < 2; nt++)
#pragma unroll
                for (int rr = 0; rr < 4; rr++) O[mt][nt][rr] *= al[mt * 4 + rr];
        __syncthreads();
#pragma unroll
        for (int mt = 0; mt < 4; mt++)
#pragma unroll
            for (int rr = 0; rr < 4; rr++) {
                const int idx = mt * 4 + rr;
                const int ri = mt * 16 + quad * 4 + rr;
                const float4 s4 = *(const float4*)&redS[ri * 4];
                l_i[idx] = l_i[idx] * al[idx] + (s4.x + s4.y + s4.z + s4.w);
            }

        // ---- PV in two 64-key halves (Ps 64x72 bf16, padded) ----
#pragma unroll
        for (int half = 0; half < 2; half++) {
            if ((wave >> 1) == half) {
                const int kc = wn - half * 64;   // 0 or 32
#pragma unroll
                for (int mt = 0; mt < 4; mt++)
#pragma unroll
                    for (int rr = 0; rr < 4; rr++) {
                        const int ri = mt * 16 + quad * 4 + rr;
                        Ps[ri * 72 + kc + fr]      = __float2bfloat16(S[mt][0][rr]);
                        Ps[ri * 72 + kc + 16 + fr] = __float2bfloat16(S[mt][1][rr]);
                    }
            }
#pragma unroll
            for (int vc = 0; vc < 2; vc++) {
                const int kb = k0 + half * 64 + vc * 32;
                GLOAD_LDS16(vT + ((size_t)(h * 128 + trow)) * 2048 + kb + tcol,      (char*)sVt + loff);
                GLOAD_LDS16(vT + ((size_t)(h * 128 + 64 + trow)) * 2048 + kb + tcol, (char*)sVt + 4096 + loff);
                __syncthreads();
                bf16x8 ap[4], bv[2];
#pragma unroll
                for (int mt = 0; mt < 4; mt++)
                    ap[mt] = *(const bf16x8*)&Ps[(mt * 16 + fr) * 72 + vc * 32 + quad * 8];
#pragma unroll
                for (int nt = 0; nt < 2; nt++)
                    bv[nt] = *(const bf16x8*)&sVt[(wn + nt * 16 + fr) * 32 + quad * 8];
#pragma unroll
                for (int mt = 0; mt < 4; mt++)
#pragma unroll
                    for (int nt = 0; nt < 2; nt++)
                        O[mt][nt] = __builtin_amdgcn_mfma_f32_16x16x32_bf16(
                            ap[mt], bv[nt], O[mt][nt], 0, 0, 0);
                __syncthreads();
            }
        }
    }

    // ---- partial store: O bf16, m, l ----
    const int g = h * 80 + sidx;
    char* base = (g < PART1_CAP) ? part1 + (size_t)g * SLICE_BYTES
                                 : part2 + (size_t)(g - PART1_CAP) * SLICE_BYTES;
    bf* Op = (bf*)base;
    float* mp = (float*)(base + 16384);
    float* lp = (float*)(base + 16640);
#pragma unroll
    for (int mt = 0; mt < 4; mt++)
#pragma unroll
        for (int rr = 0; rr < 4; rr++) {
            const int idx = mt * 4 + rr;
            const int ri = mt * 16 + quad * 4 + rr;
#pragma unroll
            for (int nt = 0; nt < 2; nt++)
                Op[ri * 128 + wn + nt * 16 + fr] = __float2bfloat16(O[mt][nt][rr]);
            if (wave == 0 && fr == 0) { mp[ri] = m_i[idx]; lp[ri] = l_i[idx]; }
        }
}

// ---------------------------------------------------------------------------
// Merge split-K partials: y[row,h,:] = sum_s w_s * O_s / sum_s w_s l_s.
// Grid 512 = 16 heads x 32 q-tiles.
// ---------------------------------------------------------------------------
__global__ __launch_bounds__(256) void attn_merge(
    const char* __restrict__ part1, const char* __restrict__ part2,
    bf* __restrict__ yh)
{
    const int h = blockIdx.x & 15, qt = blockIdx.x >> 4;
    const int a = qt >> 3, b = qt & 7;
    const int sidx0 = 4 * a * (a + 1) + b * (a + 1);
    const int nst = a + 1;
    const int tid = threadIdx.x;
    const int r = tid >> 2;
    const int c0 = (tid & 3) * 32;

    const char* bases[4];
    float m_s[4], l_s[4];
    for (int s = 0; s < nst; s++) {
        const int g = h * 80 + sidx0 + s;
        bases[s] = (g < PART1_CAP) ? part1 + (size_t)g * SLICE_BYTES
                                   : part2 + (size_t)(g - PART1_CAP) * SLICE_BYTES;
        m_s[s] = ((const float*)(bases[s] + 16384))[r];
        l_s[s] = ((const float*)(bases[s] + 16640))[r];
    }
    float M = -INFINITY;
    for (int s = 0; s < nst; s++) M = fmaxf(M, m_s[s]);
    float denom = 0.0f;
    for (int s = 0; s < nst; s++) denom += __expf(m_s[s] - M) * l_s[s];
    float w[4];
    for (int s = 0; s < nst; s++) w[s] = __expf(m_s[s] - M) / denom;

    const int row = qt * 64 + r;
    bf* dst = yh + ((size_t)row * 16 + h) * 128 + c0;
#pragma unroll
    for (int cc = 0; cc < 32; cc += 8) {
        float acc[8] = {0, 0, 0, 0, 0, 0, 0, 0};
        for (int s = 0; s < nst; s++) {
            const bf16x8 ov = *(const bf16x8*)((const bf*)bases[s] + r * 128 + c0 + cc);
#pragma unroll
            for (int u = 0; u < 8; u++) {
                union { short s16; bf b16; } cv; cv.s16 = ov[u];
                acc[u] += w[s] * __bfloat162float(cv.b16);
            }
        }
#pragma unroll
        for (int u = 0; u < 8; u++) dst[cc + u] = __float2bfloat16(acc[u]);
    }
}

// ---------------------------------------------------------------------------
// Workspace (peak 84.4 MB, <= 86.6 MB proven):
//  A  @0        : xh(8.39) xl(8.39) -> yh(8.39)@0, vT(8.39)@8.39
//  AR @16.78    : (16.78) GEMM temporaries -> attn partials region1 -> woh
//  persistent   : qh@33.55 ql@46.14 knh@58.72 knl@67.11 vh@75.50(->partials
//                 region2) kpeh@83.89 kpel@84.15
// ---------------------------------------------------------------------------
extern "C" void kernel_launch(void* const* d_in, const int* in_sizes, int n_in,
                              void* d_out, int out_size, void* d_ws, size_t ws_size,
                              hipStream_t stream)
{
    const float* x        = (const float*)d_in[0];
    const float* freqs    = (const float*)d_in[1];
    const float* wq_a     = (const float*)d_in[3];
    const float* q_norm_w = (const float*)d_in[4];
    const float* wq_b     = (const float*)d_in[5];
    const float* wkv_a    = (const float*)d_in[6];
    const float* kv_norm_w= (const float*)d_in[7];
    const float* wkv_b    = (const float*)d_in[8];
    const float* wo       = (const float*)d_in[9];
    float* out            = (float*)d_out;

    char* ws = (char*)d_ws;
    bf* xh = (bf*)(ws);
    bf* xl = (bf*)(ws + 8388608);
    bf* yh = (bf*)(ws);                   // after x dead
    bf* vT = (bf*)(ws + 8388608);         // after x dead
    char* AR = ws + 16777216;
    bf*    wah    = (bf*)(AR);
    bf*    wal    = (bf*)(AR + 3145728);
    float* qa     = (float*)(AR + 6291456);
    bf*    qah    = (bf*)(AR);
    bf*    qal    = (bf*)(AR + 3145728);
    bf*    wbh    = (bf*)(AR + 6291456);
    bf*    wbl    = (bf*)(AR + 11010048);
    bf*    kah    = (bf*)(AR);
    bf*    kal    = (bf*)(AR + 2359296);
    float* kvfull = (float*)(AR + 4718592);
    bf*    ckvh   = (bf*)(AR + 9437184);
    bf*    ckvl   = (bf*)(AR + 11534336);
    bf*    wvh    = (bf*)(AR);
    bf*    wvl    = (bf*)(AR + 4194304);
    char*  part1  = AR;                   // during attention
    bf*    woh    = (bf*)(AR);            // after merge
    bf* qh   = (bf*)(ws + 33554432);
    bf* ql   = (bf*)(ws + 46137344);
    bf* knh  = (bf*)(ws + 58720256);
    bf* knl  = (bf*)(ws + 67108864);
    bf* vh   = (bf*)(ws + 75497472);
    char* part2 = ws + 75497472;          // vh dead after transpose
    bf* kpeh = (bf*)(ws + 83886080);
    bf* kpel = (bf*)(ws + 84148224);

    dim3 blk(256);

    cvt_split<<<4096, blk, 0, stream>>>(x, xh, xl, D_MODEL * D_MODEL);
    cvt_split<<<1536, blk, 0, stream>>>(wq_a, wah, wal, QLORA * D_MODEL);
    gemm_split<0><<<dim3(6, 16), blk, 0, stream>>>(
        xh, xl, wah, wal, nullptr, qa, nullptr, nullptr, nullptr,
        T_DIM, QLORA, D_MODEL);
    rmsnorm_cvt<<<T_DIM, blk, 0, stream>>>(qa, QLORA, QLORA, q_norm_w, qah, qal);
    cvt_split<<<2304, blk, 0, stream>>>(wq_b, wbh, wbl, 3072 * QLORA);
    gemm_split<1><<<dim3(24, 16), blk, 0, stream>>>(
        qah, qal, wbh, wbl, freqs, nullptr, qh, ql, nullptr,
        T_DIM, 3072, QLORA);
    cvt_split<<<1152, blk, 0, stream>>>(wkv_a, kah, kal, KVFULL_D * D_MODEL);
    gemm_split<0><<<dim3(5, 16), blk, 0, stream>>>(
        xh, xl, kah, kal, nullptr, kvfull, nullptr, nullptr, nullptr,
        T_DIM, KVFULL_D, D_MODEL);
    rope_k_cvt<<<256, blk, 0, stream>>>(kvfull, freqs, kpeh, kpel);
    rmsnorm_cvt<<<T_DIM, blk, 0, stream>>>(kvfull, KVFULL_D, KVLORA, kv_norm_w, ckvh, ckvl);
    cvt_split<<<2048, blk, 0, stream>>>(wkv_b, wvh, wvl, 4096 * KVLORA);
    gemm_split<2><<<dim3(32, 16), blk, 0, stream>>>(
        ckvh, ckvl, wvh, wvl, nullptr, nullptr, knh, knl, vh,
        T_DIM, 4096, KVLORA);
    transpose_v<<<dim3(64, 4, 16), blk, 0, stream>>>(vh, vT);
    attn_mfma<<<dim3(1280), blk, 0, stream>>>(
        qh, ql, knh, knl, kpeh, kpel, vT, part1, part2);
    attn_merge<<<dim3(512), blk, 0, stream>>>(part1, part2, yh);
    cvt_hi<<<4096, blk, 0, stream>>>(wo, woh, D_MODEL * D_MODEL);
    gemm_bf16<<<dim3(16, 16), blk, 0, stream>>>(
        yh, woh, out, T_DIM, D_MODEL, D_MODEL);
}

// Round 8
// 728.172 us; speedup vs baseline: 1.5927x; 1.1007x over previous
//
#include <hip/hip_runtime.h>
#include <hip/hip_bf16.h>
#include <math.h>

// ---------------------------------------------------------------------------
// DeepSeek MLA forward. Round 8:
//  - attn: XCD-affinity swizzle (xcd = bid&7 -> heads 2x,2x+1) so each head's
//    K/V/Q stay in one XCD's L2 (R7 FETCH=246 MB was cross-XCD re-fetch).
//  - attn PV: both V chunks preloaded per half; 1 barrier fewer per half.
//  - qa / kvfull GEMMs: 64x64-tile split variant (384 / 288 blocks) —
//    the 128-tile version left >half the CUs idle at N=768/576.
//  - attn_mfma keeps __launch_bounds__(256,2) (R6: (256,4) => spill).
// ---------------------------------------------------------------------------

#define T_DIM 2048
#define HEADS 16
#define D_MODEL 2048
#define NOPE_D 128
#define ROPE_D 64
#define QKD_D 192
#define VD_D 128
#define QLORA 768
#define KVLORA 512
#define KVFULL_D 576
#define SOFTSCALE -96.0f
#define EPS_RMS 1e-6f

typedef __hip_bfloat16 bf;
typedef __attribute__((ext_vector_type(8))) short bf16x8;
typedef __attribute__((ext_vector_type(4))) float f32x4;

#define SLICE_BYTES 16896   // O 64x128 bf16 (16384) + m 64 f32 + l 64 f32
#define PART1_CAP 992       // slices in 16.78 MB arena

#define GLOAD_LDS16(gptr, lptr)                                               \
    __builtin_amdgcn_global_load_lds(                                         \
        (const __attribute__((address_space(1))) unsigned int*)(gptr),        \
        (__attribute__((address_space(3))) unsigned int*)(lptr), 16, 0, 0)

__device__ __forceinline__ void split2(float v, bf* hi, bf* lo) {
    bf h = __float2bfloat16(v);
    *hi = h;
    *lo = __float2bfloat16(v - __bfloat162float(h));
}

// ---------------------------------------------------------------------------
__global__ __launch_bounds__(256) void cvt_split(
    const float* __restrict__ in, bf* __restrict__ hi, bf* __restrict__ lo, int n)
{
    const int i = (blockIdx.x * 256 + threadIdx.x) * 4;
    if (i >= n) return;
    float4 v = *(const float4*)&in[i];
    float vv[4] = {v.x, v.y, v.z, v.w};
#pragma unroll
    for (int u = 0; u < 4; u++) split2(vv[u], &hi[i + u], &lo[i + u]);
}

__global__ __launch_bounds__(256) void cvt_hi(
    const float* __restrict__ in, bf* __restrict__ hi, int n)
{
    const int i = (blockIdx.x * 256 + threadIdx.x) * 4;
    if (i >= n) return;
    float4 v = *(const float4*)&in[i];
    hi[i + 0] = __float2bfloat16(v.x);
    hi[i + 1] = __float2bfloat16(v.y);
    hi[i + 2] = __float2bfloat16(v.z);
    hi[i + 3] = __float2bfloat16(v.w);
}

// ---------------------------------------------------------------------------
__global__ __launch_bounds__(256) void rmsnorm_cvt(
    const float* __restrict__ in, int ld, int D, const float* __restrict__ w,
    bf* __restrict__ hi, bf* __restrict__ lo)
{
    const int row = blockIdx.x;
    const float* r = in + (size_t)row * ld;
    float ss = 0.0f;
    for (int i = threadIdx.x; i < D; i += 256) { float v = r[i]; ss += v * v; }
#pragma unroll
    for (int o = 32; o > 0; o >>= 1) ss += __shfl_down(ss, o, 64);
    __shared__ float red[4];
    if ((threadIdx.x & 63) == 0) red[threadIdx.x >> 6] = ss;
    __syncthreads();
    ss = red[0] + red[1] + red[2] + red[3];
    const float scale = rsqrtf(ss / (float)D + EPS_RMS);
    for (int i = threadIdx.x; i < D; i += 256) {
        const float v = r[i] * scale * w[i];
        split2(v, &hi[(size_t)row * D + i], &lo[(size_t)row * D + i]);
    }
}

// ---------------------------------------------------------------------------
__global__ __launch_bounds__(256) void rope_k_cvt(
    const float* __restrict__ kvfull, const float* __restrict__ freqs,
    bf* __restrict__ kpeh, bf* __restrict__ kpel)
{
    const int idx = blockIdx.x * 256 + threadIdx.x;   // 65536
    const int i = idx & 31, t = idx >> 5;
    const float f = freqs[t * 32 + i];
    float sn, cs; sincosf(f, &sn, &cs);
    const float x1 = kvfull[(size_t)t * KVFULL_D + KVLORA + 2 * i];
    const float x2 = kvfull[(size_t)t * KVFULL_D + KVLORA + 2 * i + 1];
    split2(x1 * cs - x2 * sn, &kpeh[t * 64 + 2 * i], &kpel[t * 64 + 2 * i]);
    split2(x1 * sn + x2 * cs, &kpeh[t * 64 + 2 * i + 1], &kpel[t * 64 + 2 * i + 1]);
}

// ---------------------------------------------------------------------------
__global__ __launch_bounds__(256) void transpose_v(
    const bf* __restrict__ vh, bf* __restrict__ vT)
{
    __shared__ bf s[32][33];
    const int t0 = blockIdx.x * 32, d0 = blockIdx.y * 32, h = blockIdx.z;
    const int tid = threadIdx.x;
    const int i = tid >> 3, j0 = (tid & 7) * 4;
    const bf* src = vh + ((size_t)(t0 + i) * 16 + h) * 128 + d0 + j0;
#pragma unroll
    for (int u = 0; u < 4; u++) s[i][j0 + u] = src[u];
    __syncthreads();
    const int jj = tid >> 3, i0 = (tid & 7) * 4;
    bf* dst = vT + ((size_t)h * 128 + d0 + jj) * 2048 + t0 + i0;
#pragma unroll
    for (int u = 0; u < 4; u++) dst[u] = s[i0 + u][jj];
}

// ---------------------------------------------------------------------------
// Split-bf16 GEMM (score path), 128x128 tile, 3 MFMAs.
// MODE 1: RoPE on d>=128 + split -> Oh/Ol (q). MODE 2: kn/v split write.
// ---------------------------------------------------------------------------
template <int MODE>
__global__ __launch_bounds__(256) void gemm_split(
    const bf* __restrict__ Ah, const bf* __restrict__ Al,
    const bf* __restrict__ Bh, const bf* __restrict__ Bl,
    const float* __restrict__ freqs,
    float* __restrict__ Cf, bf* __restrict__ Oh, bf* __restrict__ Ol,
    bf* __restrict__ O2, int M, int N, int K)
{
    __shared__ bf sAh[128 * 32], sAl[128 * 32];
    __shared__ bf sBh[128 * 32], sBl[128 * 32];

    const int tid = threadIdx.x;
    const int lane = tid & 63, wave = tid >> 6;
    const int row0 = blockIdx.y * 128, col0 = blockIdx.x * 128;
    const int wm = (wave & 1) * 64, wn = (wave >> 1) * 64;
    const int fr = lane & 15, quad = lane >> 4;

    f32x4 acc[4][4];
#pragma unroll
    for (int i = 0; i < 4; i++)
#pragma unroll
        for (int j = 0; j < 4; j++) acc[i][j] = (f32x4){0.f, 0.f, 0.f, 0.f};

    const int trow = tid >> 2;
    const int tcol = (tid & 3) * 8;
    const size_t ldsoff = (size_t)wave * 1024;

    for (int kt = 0; kt < K; kt += 32) {
        __syncthreads();
        GLOAD_LDS16(Ah + (size_t)(row0 + trow) * K + kt + tcol,      (char*)sAh + ldsoff);
        GLOAD_LDS16(Ah + (size_t)(row0 + 64 + trow) * K + kt + tcol, (char*)sAh + 4096 + ldsoff);
        GLOAD_LDS16(Al + (size_t)(row0 + trow) * K + kt + tcol,      (char*)sAl + ldsoff);
        GLOAD_LDS16(Al + (size_t)(row0 + 64 + trow) * K + kt + tcol, (char*)sAl + 4096 + ldsoff);
        GLOAD_LDS16(Bh + (size_t)(col0 + trow) * K + kt + tcol,      (char*)sBh + ldsoff);
        GLOAD_LDS16(Bh + (size_t)(col0 + 64 + trow) * K + kt + tcol, (char*)sBh + 4096 + ldsoff);
        GLOAD_LDS16(Bl + (size_t)(col0 + trow) * K + kt + tcol,      (char*)sBl + ldsoff);
        GLOAD_LDS16(Bl + (size_t)(col0 + 64 + trow) * K + kt + tcol, (char*)sBl + 4096 + ldsoff);
        __syncthreads();

        bf16x8 a_h[4], a_l[4], b_h[4], b_l[4];
#pragma unroll
        for (int mt = 0; mt < 4; mt++) {
            const int r = (wm + mt * 16 + fr) * 32 + quad * 8;
            a_h[mt] = *(const bf16x8*)&sAh[r];
            a_l[mt] = *(const bf16x8*)&sAl[r];
        }
#pragma unroll
        for (int nt = 0; nt < 4; nt++) {
            const int r = (wn + nt * 16 + fr) * 32 + quad * 8;
            b_h[nt] = *(const bf16x8*)&sBh[r];
            b_l[nt] = *(const bf16x8*)&sBl[r];
        }
#pragma unroll
        for (int mt = 0; mt < 4; mt++)
#pragma unroll
            for (int nt = 0; nt < 4; nt++) {
                acc[mt][nt] = __builtin_amdgcn_mfma_f32_16x16x32_bf16(
                    a_l[mt], b_h[nt], acc[mt][nt], 0, 0, 0);
                acc[mt][nt] = __builtin_amdgcn_mfma_f32_16x16x32_bf16(
                    a_h[mt], b_l[nt], acc[mt][nt], 0, 0, 0);
                acc[mt][nt] = __builtin_amdgcn_mfma_f32_16x16x32_bf16(
                    a_h[mt], b_h[nt], acc[mt][nt], 0, 0, 0);
            }
    }

#pragma unroll
    for (int mt = 0; mt < 4; mt++)
#pragma unroll
        for (int nt = 0; nt < 4; nt++) {
            const int colb = col0 + wn + nt * 16;
            const int col = colb + fr;
            if (MODE == 1) {
                const int d0 = colb % 192;
                const bool rope = (d0 >= 128);
                const int ii = (d0 + fr - 128) >> 1;
#pragma unroll
                for (int r = 0; r < 4; r++) {
                    const int row = row0 + wm + mt * 16 + quad * 4 + r;
                    float v = acc[mt][nt][r];
                    if (rope) {
                        const float other = __shfl_xor(v, 1);
                        float sn, cs; sincosf(freqs[row * 32 + ii], &sn, &cs);
                        v = (fr & 1) ? (other * sn + v * cs) : (v * cs - other * sn);
                    }
                    bf h8, l8; split2(v, &h8, &l8);
                    Oh[(size_t)row * N + col] = h8;
                    Ol[(size_t)row * N + col] = l8;
                }
            } else {
                const int hh = col >> 8;
                const int d = col & 255;
#pragma unroll
                for (int r = 0; r < 4; r++) {
                    const int row = row0 + wm + mt * 16 + quad * 4 + r;
                    const float v = acc[mt][nt][r];
                    if (d < 128) {
                        bf h8, l8; split2(v, &h8, &l8);
                        Oh[(size_t)row * 2048 + hh * 128 + d] = h8;
                        Ol[(size_t)row * 2048 + hh * 128 + d] = l8;
                    } else {
                        O2[(size_t)row * 2048 + hh * 128 + (d - 128)] = __float2bfloat16(v);
                    }
                }
            }
        }
}

// ---------------------------------------------------------------------------
// Split-bf16 GEMM, 64x64 tile (small-N shapes: qa N=768, kvfull N=576).
// 4 waves x 32x32; grid (N/64, M/64) -> 288-384 blocks (full CU coverage).
// ---------------------------------------------------------------------------
__global__ __launch_bounds__(256) void gemm_split64(
    const bf* __restrict__ Ah, const bf* __restrict__ Al,
    const bf* __restrict__ Bh, const bf* __restrict__ Bl,
    float* __restrict__ Cf, int M, int N, int K)
{
    __shared__ bf sAh[64 * 32], sAl[64 * 32];
    __shared__ bf sBh[64 * 32], sBl[64 * 32];

    const int tid = threadIdx.x;
    const int lane = tid & 63, wave = tid >> 6;
    const int row0 = blockIdx.y * 64, col0 = blockIdx.x * 64;
    const int wm = (wave & 1) * 32, wn = (wave >> 1) * 32;
    const int fr = lane & 15, quad = lane >> 4;

    f32x4 acc[2][2];
#pragma unroll
    for (int i = 0; i < 2; i++)
#pragma unroll
        for (int j = 0; j < 2; j++) acc[i][j] = (f32x4){0.f, 0.f, 0.f, 0.f};

    const int trow = tid >> 2;
    const int tcol = (tid & 3) * 8;
    const size_t ldsoff = (size_t)wave * 1024;

    for (int kt = 0; kt < K; kt += 32) {
        __syncthreads();
        GLOAD_LDS16(Ah + (size_t)(row0 + trow) * K + kt + tcol, (char*)sAh + ldsoff);
        GLOAD_LDS16(Al + (size_t)(row0 + trow) * K + kt + tcol, (char*)sAl + ldsoff);
        GLOAD_LDS16(Bh + (size_t)(col0 + trow) * K + kt + tcol, (char*)sBh + ldsoff);
        GLOAD_LDS16(Bl + (size_t)(col0 + trow) * K + kt + tcol, (char*)sBl + ldsoff);
        __syncthreads();

        bf16x8 a_h[2], a_l[2], b_h[2], b_l[2];
#pragma unroll
        for (int mt = 0; mt < 2; mt++) {
            const int r = (wm + mt * 16 + fr) * 32 + quad * 8;
            a_h[mt] = *(const bf16x8*)&sAh[r];
            a_l[mt] = *(const bf16x8*)&sAl[r];
        }
#pragma unroll
        for (int nt = 0; nt < 2; nt++) {
            const int r = (wn + nt * 16 + fr) * 32 + quad * 8;
            b_h[nt] = *(const bf16x8*)&sBh[r];
            b_l[nt] = *(const bf16x8*)&sBl[r];
        }
#pragma unroll
        for (int mt = 0; mt < 2; mt++)
#pragma unroll
            for (int nt = 0; nt < 2; nt++) {
                acc[mt][nt] = __builtin_amdgcn_mfma_f32_16x16x32_bf16(
                    a_l[mt], b_h[nt], acc[mt][nt], 0, 0, 0);
                acc[mt][nt] = __builtin_amdgcn_mfma_f32_16x16x32_bf16(
                    a_h[mt], b_l[nt], acc[mt][nt], 0, 0, 0);
                acc[mt][nt] = __builtin_amdgcn_mfma_f32_16x16x32_bf16(
                    a_h[mt], b_h[nt], acc[mt][nt], 0, 0, 0);
            }
    }

#pragma unroll
    for (int mt = 0; mt < 2; mt++)
#pragma unroll
        for (int nt = 0; nt < 2; nt++)
#pragma unroll
            for (int r = 0; r < 4; r++)
                Cf[(size_t)(row0 + wm + mt * 16 + quad * 4 + r) * N +
                   col0 + wn + nt * 16 + fr] = acc[mt][nt][r];
}

// ---------------------------------------------------------------------------
// Plain bf16 GEMM (post-softmax out-projection): C = A @ B^T, single MFMA.
// ---------------------------------------------------------------------------
__global__ __launch_bounds__(256) void gemm_bf16(
    const bf* __restrict__ Ah, const bf* __restrict__ Bh,
    float* __restrict__ Cf, int M, int N, int K)
{
    __shared__ bf sAh[128 * 32];
    __shared__ bf sBh[128 * 32];

    const int tid = threadIdx.x;
    const int lane = tid & 63, wave = tid >> 6;
    const int row0 = blockIdx.y * 128, col0 = blockIdx.x * 128;
    const int wm = (wave & 1) * 64, wn = (wave >> 1) * 64;
    const int fr = lane & 15, quad = lane >> 4;

    f32x4 acc[4][4];
#pragma unroll
    for (int i = 0; i < 4; i++)
#pragma unroll
        for (int j = 0; j < 4; j++) acc[i][j] = (f32x4){0.f, 0.f, 0.f, 0.f};

    const int trow = tid >> 2;
    const int tcol = (tid & 3) * 8;
    const size_t ldsoff = (size_t)wave * 1024;

    for (int kt = 0; kt < K; kt += 32) {
        __syncthreads();
        GLOAD_LDS16(Ah + (size_t)(row0 + trow) * K + kt + tcol,      (char*)sAh + ldsoff);
        GLOAD_LDS16(Ah + (size_t)(row0 + 64 + trow) * K + kt + tcol, (char*)sAh + 4096 + ldsoff);
        GLOAD_LDS16(Bh + (size_t)(col0 + trow) * K + kt + tcol,      (char*)sBh + ldsoff);
        GLOAD_LDS16(Bh + (size_t)(col0 + 64 + trow) * K + kt + tcol, (char*)sBh + 4096 + ldsoff);
        __syncthreads();

        bf16x8 a_h[4], b_h[4];
#pragma unroll
        for (int mt = 0; mt < 4; mt++)
            a_h[mt] = *(const bf16x8*)&sAh[(wm + mt * 16 + fr) * 32 + quad * 8];
#pragma unroll
        for (int nt = 0; nt < 4; nt++)
            b_h[nt] = *(const bf16x8*)&sBh[(wn + nt * 16 + fr) * 32 + quad * 8];
#pragma unroll
        for (int mt = 0; mt < 4; mt++)
#pragma unroll
            for (int nt = 0; nt < 4; nt++)
                acc[mt][nt] = __builtin_amdgcn_mfma_f32_16x16x32_bf16(
                    a_h[mt], b_h[nt], acc[mt][nt], 0, 0, 0);
    }

#pragma unroll
    for (int mt = 0; mt < 4; mt++)
#pragma unroll
        for (int nt = 0; nt < 4; nt++)
#pragma unroll
            for (int r = 0; r < 4; r++)
                Cf[(size_t)(row0 + wm + mt * 16 + quad * 4 + r) * N +
                   col0 + wn + nt * 16 + fr] = acc[mt][nt][r];
}

// ---------------------------------------------------------------------------
// Split-K MFMA flash attention. 1280 blocks; XCD-affinity mapping:
// xcd = bid&7 serves heads {2*xcd, 2*xcd+1} only -> each head's K/V/Q stay
// in one XCD's 4 MB L2 (R7: heads scattered -> 246 MB HBM re-fetch).
// __launch_bounds__(256,2): (256,4) spilled (R6). Ps padded stride 72.
// ---------------------------------------------------------------------------
__global__ __launch_bounds__(256, 2) void attn_mfma(
    const bf* __restrict__ qh, const bf* __restrict__ ql,
    const bf* __restrict__ knh, const bf* __restrict__ knl,
    const bf* __restrict__ kpeh, const bf* __restrict__ kpel,
    const bf* __restrict__ vT,
    char* __restrict__ part1, char* __restrict__ part2)
{
    const int bid = blockIdx.x;
    const int xcd = bid & 7;
    const int rr8 = bid >> 3;                 // 0..159
    const int h = (xcd << 1) | (rr8 & 1);
    const int sidx = rr8 >> 1;                // 0..79
    int qt, s;
    if (sidx < 8)       { qt = sidx; s = 0; }
    else if (sidx < 24) { const int r = sidx - 8;  qt = 8  + (r >> 1); s = r & 1; }
    else if (sidx < 48) { const int r = sidx - 24; qt = 16 + r / 3;    s = r % 3; }
    else                { const int r = sidx - 48; qt = 24 + (r >> 2); s = r & 3; }

    const int tid = threadIdx.x;
    const int lane = tid & 63, wave = tid >> 6;
    const int fr = lane & 15, quad = lane >> 4;
    const int wn = wave * 32;

    __shared__ __align__(16) char smem[35840];
    bf* sQh = (bf*)(smem);
    bf* sQl = (bf*)(smem + 4096);
    bf* sKh = (bf*)(smem + 8192);
    bf* sKl = (bf*)(smem + 16384);
    bf* sVt = (bf*)(smem + 8192);         // 16 KB alias over sKh+sKl (dead in PV)
    bf* Ps  = (bf*)(smem + 24576);        // [64][72] padded
    float* redM = (float*)(smem + 33792); // [64][4]
    float* redS = (float*)(smem + 34816); // [64][4]

    float m_i[16], l_i[16], al[16];
    f32x4 O[4][2];
#pragma unroll
    for (int i = 0; i < 16; i++) { m_i[i] = -INFINITY; l_i[i] = 0.0f; }
#pragma unroll
    for (int mt = 0; mt < 4; mt++)
#pragma unroll
        for (int nt = 0; nt < 2; nt++) O[mt][nt] = (f32x4){0.f, 0.f, 0.f, 0.f};

    const int q0 = qt * 64;
    const int kstart = s * 512;
    const int kend = min(kstart + 512, (qt + 1) * 64);
    const int trow = tid >> 2, tcol = (tid & 3) * 8;
    const size_t loff = (size_t)wave * 1024;

    for (int k0 = kstart; k0 < kend; k0 += 128) {
        f32x4 S[4][2];
#pragma unroll
        for (int mt = 0; mt < 4; mt++)
#pragma unroll
            for (int nt = 0; nt < 2; nt++) S[mt][nt] = (f32x4){0.f, 0.f, 0.f, 0.f};

        // ---- S = Q.K^T over 192 dims, 6 chunks of 32 ----
        for (int ch = 0; ch < 6; ch++) {
            const int d0 = ch * 32;
            __syncthreads();
            GLOAD_LDS16(qh + ((size_t)(q0 + trow) * 16 + h) * 192 + d0 + tcol, (char*)sQh + loff);
            GLOAD_LDS16(ql + ((size_t)(q0 + trow) * 16 + h) * 192 + d0 + tcol, (char*)sQl + loff);
            if (d0 < 128) {
                GLOAD_LDS16(knh + ((size_t)(k0 + trow) * 16 + h) * 128 + d0 + tcol,      (char*)sKh + loff);
                GLOAD_LDS16(knh + ((size_t)(k0 + 64 + trow) * 16 + h) * 128 + d0 + tcol, (char*)sKh + 4096 + loff);
                GLOAD_LDS16(knl + ((size_t)(k0 + trow) * 16 + h) * 128 + d0 + tcol,      (char*)sKl + loff);
                GLOAD_LDS16(knl + ((size_t)(k0 + 64 + trow) * 16 + h) * 128 + d0 + tcol, (char*)sKl + 4096 + loff);
            } else {
                GLOAD_LDS16(kpeh + (size_t)(k0 + trow) * 64 + (d0 - 128) + tcol,      (char*)sKh + loff);
                GLOAD_LDS16(kpeh + (size_t)(k0 + 64 + trow) * 64 + (d0 - 128) + tcol, (char*)sKh + 4096 + loff);
                GLOAD_LDS16(kpel + (size_t)(k0 + trow) * 64 + (d0 - 128) + tcol,      (char*)sKl + loff);
                GLOAD_LDS16(kpel + (size_t)(k0 + 64 + trow) * 64 + (d0 - 128) + tcol, (char*)sKl + 4096 + loff);
            }
            __syncthreads();

            bf16x8 a_h[4], a_l[4], b_h[2], b_l[2];
#pragma unroll
            for (int mt = 0; mt < 4; mt++) {
                const int r = (mt * 16 + fr) * 32 + quad * 8;
                a_h[mt] = *(const bf16x8*)&sQh[r];
                a_l[mt] = *(const bf16x8*)&sQl[r];
            }
#pragma unroll
            for (int nt = 0; nt < 2; nt++) {
                const int r = (wn + nt * 16 + fr) * 32 + quad * 8;
                b_h[nt] = *(const bf16x8*)&sKh[r];
                b_l[nt] = *(const bf16x8*)&sKl[r];
            }
#pragma unroll
            for (int mt = 0; mt < 4; mt++)
#pragma unroll
                for (int nt = 0; nt < 2; nt++) {
                    S[mt][nt] = __builtin_amdgcn_mfma_f32_16x16x32_bf16(
                        a_l[mt], b_h[nt], S[mt][nt], 0, 0, 0);
                    S[mt][nt] = __builtin_amdgcn_mfma_f32_16x16x32_bf16(
                        a_h[mt], b_l[nt], S[mt][nt], 0, 0, 0);
                    S[mt][nt] = __builtin_amdgcn_mfma_f32_16x16x32_bf16(
                        a_h[mt], b_h[nt], S[mt][nt], 0, 0, 0);
                }
        }

        // ---- online softmax (fp32, block-wide row reductions) ----
#pragma unroll
        for (int mt = 0; mt < 4; mt++)
#pragma unroll
            for (int rr = 0; rr < 4; rr++) {
                const int ri = mt * 16 + quad * 4 + rr;
                const int rowg = q0 + ri;
                float v0 = S[mt][0][rr] * SOFTSCALE;
                float v1 = S[mt][1][rr] * SOFTSCALE;
                if (k0 + wn + fr > rowg)      v0 = -INFINITY;
                if (k0 + wn + 16 + fr > rowg) v1 = -INFINITY;
                S[mt][0][rr] = v0; S[mt][1][rr] = v1;
                float pm = fmaxf(v0, v1);
#pragma unroll
                for (int o = 1; o < 16; o <<= 1) pm = fmaxf(pm, __shfl_xor(pm, o, 64));
                if (fr == 0) redM[ri * 4 + wave] = pm;
            }
        __syncthreads();
#pragma unroll
        for (int mt = 0; mt < 4; mt++)
#pragma unroll
            for (int rr = 0; rr < 4; rr++) {
                const int idx = mt * 4 + rr;
                const int ri = mt * 16 + quad * 4 + rr;
                const float4 g = *(const float4*)&redM[ri * 4];
                const float gm = fmaxf(fmaxf(g.x, g.y), fmaxf(g.z, g.w));
                const float mn = fmaxf(m_i[idx], gm);
                al[idx] = __expf(m_i[idx] - mn);
                m_i[idx] = mn;
                const float p0 = __expf(S[mt][0][rr] - mn);
                const float p1 = __expf(S[mt][1][rr] - mn);
                S[mt][0][rr] = p0; S[mt][1][rr] = p1;   // keep p for PV store
                float ps = p0 + p1;
#pragma unroll
                for (int o = 1; o < 16; o <<= 1) ps += __shfl_xor(ps, o, 64);
                if (fr == 0) redS[ri * 4 + wave] = ps;
            }
#pragma unroll
        for (int mt = 0; mt < 4; mt++)
#pragma unroll
            for (int nt = 0; nt < 2; nt++)
#pragma unroll
                for (int rr = 0; rr < 4; rr++) O[mt][nt][rr] *= al[mt * 4 + rr];
        __syncthreads();
#pragma unroll
        for (int mt = 0; mt < 4; mt++)
#pragma unroll
            for (int rr = 0; rr < 4; rr++) {
                const int idx = mt * 4 + rr;
                const int ri = mt * 16 + quad * 4 + rr;
                const float4 s4 = *(const float4*)&redS[ri * 4];
                l_i[idx] = l_i[idx] * al[idx] + (s4.x + s4.y + s4.z + s4.w);
            }

        // ---- PV: two 64-key halves; both 32-key V chunks preloaded ----
#pragma unroll
        for (int half = 0; half < 2; half++) {
            if (half) __syncthreads();   // prior Ps/sVt readers done
            if ((wave >> 1) == half) {
                const int kc = wn - half * 64;   // 0 or 32
#pragma unroll
                for (int mt = 0; mt < 4; mt++)
#pragma unroll
                    for (int rr = 0; rr < 4; rr++) {
                        const int ri = mt * 16 + quad * 4 + rr;
                        Ps[ri * 72 + kc + fr]      = __float2bfloat16(S[mt][0][rr]);
                        Ps[ri * 72 + kc + 16 + fr] = __float2bfloat16(S[mt][1][rr]);
                    }
            }
            const int kb = k0 + half * 64;
            GLOAD_LDS16(vT + ((size_t)(h * 128 + trow)) * 2048 + kb + tcol,           (char*)sVt + loff);
            GLOAD_LDS16(vT + ((size_t)(h * 128 + 64 + trow)) * 2048 + kb + tcol,      (char*)sVt + 4096 + loff);
            GLOAD_LDS16(vT + ((size_t)(h * 128 + trow)) * 2048 + kb + 32 + tcol,      (char*)sVt + 8192 + loff);
            GLOAD_LDS16(vT + ((size_t)(h * 128 + 64 + trow)) * 2048 + kb + 32 + tcol, (char*)sVt + 12288 + loff);
            __syncthreads();
#pragma unroll
            for (int vc = 0; vc < 2; vc++) {
                bf16x8 ap[4], bv[2];
#pragma unroll
                for (int mt = 0; mt < 4; mt++)
                    ap[mt] = *(const bf16x8*)&Ps[(mt * 16 + fr) * 72 + vc * 32 + quad * 8];
#pragma unroll
                for (int nt = 0; nt < 2; nt++)
                    bv[nt] = *(const bf16x8*)&sVt[vc * 4096 + (wn + nt * 16 + fr) * 32 + quad * 8];
#pragma unroll
                for (int mt = 0; mt < 4; mt++)
#pragma unroll
                    for (int nt = 0; nt < 2; nt++)
                        O[mt][nt] = __builtin_amdgcn_mfma_f32_16x16x32_bf16(
                            ap[mt], bv[nt], O[mt][nt], 0, 0, 0);
            }
        }
    }

    // ---- partial store: O bf16, m, l ----
    const int g = h * 80 + sidx;
    char* base = (g < PART1_CAP) ? part1 + (size_t)g * SLICE_BYTES
                                 : part2 + (size_t)(g - PART1_CAP) * SLICE_BYTES;
    bf* Op = (bf*)base;
    float* mp = (float*)(base + 16384);
    float* lp = (float*)(base + 16640);
#pragma unroll
    for (int mt = 0; mt < 4; mt++)
#pragma unroll
        for (int rr = 0; rr < 4; rr++) {
            const int idx = mt * 4 + rr;
            const int ri = mt * 16 + quad * 4 + rr;
#pragma unroll
            for (int nt = 0; nt < 2; nt++)
                Op[ri * 128 + wn + nt * 16 + fr] = __float2bfloat16(O[mt][nt][rr]);
            if (wave == 0 && fr == 0) { mp[ri] = m_i[idx]; lp[ri] = l_i[idx]; }
        }
}

// ---------------------------------------------------------------------------
// Merge split-K partials: y[row,h,:] = sum_s w_s * O_s / sum_s w_s l_s.
// ---------------------------------------------------------------------------
__global__ __launch_bounds__(256) void attn_merge(
    const char* __restrict__ part1, const char* __restrict__ part2,
    bf* __restrict__ yh)
{
    const int h = blockIdx.x & 15, qt = blockIdx.x >> 4;
    const int a = qt >> 3, b = qt & 7;
    const int sidx0 = 4 * a * (a + 1) + b * (a + 1);
    const int nst = a + 1;
    const int tid = threadIdx.x;
    const int r = tid >> 2;
    const int c0 = (tid & 3) * 32;

    const char* bases[4];
    float m_s[4], l_s[4];
    for (int s = 0; s < nst; s++) {
        const int g = h * 80 + sidx0 + s;
        bases[s] = (g < PART1_CAP) ? part1 + (size_t)g * SLICE_BYTES
                                   : part2 + (size_t)(g - PART1_CAP) * SLICE_BYTES;
        m_s[s] = ((const float*)(bases[s] + 16384))[r];
        l_s[s] = ((const float*)(bases[s] + 16640))[r];
    }
    float M = -INFINITY;
    for (int s = 0; s < nst; s++) M = fmaxf(M, m_s[s]);
    float denom = 0.0f;
    for (int s = 0; s < nst; s++) denom += __expf(m_s[s] - M) * l_s[s];
    float w[4];
    for (int s = 0; s < nst; s++) w[s] = __expf(m_s[s] - M) / denom;

    const int row = qt * 64 + r;
    bf* dst = yh + ((size_t)row * 16 + h) * 128 + c0;
#pragma unroll
    for (int cc = 0; cc < 32; cc += 8) {
        float acc[8] = {0, 0, 0, 0, 0, 0, 0, 0};
        for (int s = 0; s < nst; s++) {
            const bf16x8 ov = *(const bf16x8*)((const bf*)bases[s] + r * 128 + c0 + cc);
#pragma unroll
            for (int u = 0; u < 8; u++) {
                union { short s16; bf b16; } cv; cv.s16 = ov[u];
                acc[u] += w[s] * __bfloat162float(cv.b16);
            }
        }
#pragma unroll
        for (int u = 0; u < 8; u++) dst[cc + u] = __float2bfloat16(acc[u]);
    }
}

// ---------------------------------------------------------------------------
// Workspace (peak 84.4 MB):
//  A  @0        : xh(8.39) xl(8.39) -> yh@0, vT@8.39
//  AR @16.78    : (16.78) GEMM temporaries -> attn partials region1 -> woh
//  persistent   : qh@33.55 ql@46.14 knh@58.72 knl@67.11 vh@75.50(->partials
//                 region2) kpeh@83.89 kpel@84.15
// ---------------------------------------------------------------------------
extern "C" void kernel_launch(void* const* d_in, const int* in_sizes, int n_in,
                              void* d_out, int out_size, void* d_ws, size_t ws_size,
                              hipStream_t stream)
{
    const float* x        = (const float*)d_in[0];
    const float* freqs    = (const float*)d_in[1];
    const float* wq_a     = (const float*)d_in[3];
    const float* q_norm_w = (const float*)d_in[4];
    const float* wq_b     = (const float*)d_in[5];
    const float* wkv_a    = (const float*)d_in[6];
    const float* kv_norm_w= (const float*)d_in[7];
    const float* wkv_b    = (const float*)d_in[8];
    const float* wo       = (const float*)d_in[9];
    float* out            = (float*)d_out;

    char* ws = (char*)d_ws;
    bf* xh = (bf*)(ws);
    bf* xl = (bf*)(ws + 8388608);
    bf* yh = (bf*)(ws);                   // after x dead
    bf* vT = (bf*)(ws + 8388608);         // after x dead
    char* AR = ws + 16777216;
    bf*    wah    = (bf*)(AR);
    bf*    wal    = (bf*)(AR + 3145728);
    float* qa     = (float*)(AR + 6291456);
    bf*    qah    = (bf*)(AR);
    bf*    qal    = (bf*)(AR + 3145728);
    bf*    wbh    = (bf*)(AR + 6291456);
    bf*    wbl    = (bf*)(AR + 11010048);
    bf*    kah    = (bf*)(AR);
    bf*    kal    = (bf*)(AR + 2359296);
    float* kvfull = (float*)(AR + 4718592);
    bf*    ckvh   = (bf*)(AR + 9437184);
    bf*    ckvl   = (bf*)(AR + 11534336);
    bf*    wvh    = (bf*)(AR);
    bf*    wvl    = (bf*)(AR + 4194304);
    char*  part1  = AR;                   // during attention
    bf*    woh    = (bf*)(AR);            // after merge
    bf* qh   = (bf*)(ws + 33554432);
    bf* ql   = (bf*)(ws + 46137344);
    bf* knh  = (bf*)(ws + 58720256);
    bf* knl  = (bf*)(ws + 67108864);
    bf* vh   = (bf*)(ws + 75497472);
    char* part2 = ws + 75497472;          // vh dead after transpose
    bf* kpeh = (bf*)(ws + 83886080);
    bf* kpel = (bf*)(ws + 84148224);

    dim3 blk(256);

    cvt_split<<<4096, blk, 0, stream>>>(x, xh, xl, D_MODEL * D_MODEL);
    cvt_split<<<1536, blk, 0, stream>>>(wq_a, wah, wal, QLORA * D_MODEL);
    gemm_split64<<<dim3(12, 32), blk, 0, stream>>>(
        xh, xl, wah, wal, qa, T_DIM, QLORA, D_MODEL);
    rmsnorm_cvt<<<T_DIM, blk, 0, stream>>>(qa, QLORA, QLORA, q_norm_w, qah, qal);
    cvt_split<<<2304, blk, 0, stream>>>(wq_b, wbh, wbl, 3072 * QLORA);
    gemm_split<1><<<dim3(24, 16), blk, 0, stream>>>(
        qah, qal, wbh, wbl, freqs, nullptr, qh, ql, nullptr,
        T_DIM, 3072, QLORA);
    cvt_split<<<1152, blk, 0, stream>>>(wkv_a, kah, kal, KVFULL_D * D_MODEL);
    gemm_split64<<<dim3(9, 32), blk, 0, stream>>>(
        xh, xl, kah, kal, kvfull, T_DIM, KVFULL_D, D_MODEL);
    rope_k_cvt<<<256, blk, 0, stream>>>(kvfull, freqs, kpeh, kpel);
    rmsnorm_cvt<<<T_DIM, blk, 0, stream>>>(kvfull, KVFULL_D, KVLORA, kv_norm_w, ckvh, ckvl);
    cvt_split<<<2048, blk, 0, stream>>>(wkv_b, wvh, wvl, 4096 * KVLORA);
    gemm_split<2><<<dim3(32, 16), blk, 0, stream>>>(
        ckvh, ckvl, wvh, wvl, nullptr, nullptr, knh, knl, vh,
        T_DIM, 4096, KVLORA);
    transpose_v<<<dim3(64, 4, 16), blk, 0, stream>>>(vh, vT);
    attn_mfma<<<dim3(1280), blk, 0, stream>>>(
        qh, ql, knh, knl, kpeh, kpel, vT, part1, part2);
    attn_merge<<<dim3(512), blk, 0, stream>>>(part1, part2, yh);
    cvt_hi<<<4096, blk, 0, stream>>>(wo, woh, D_MODEL * D_MODEL);
    gemm_bf16<<<dim3(16, 16), blk, 0, stream>>>(
        yh, woh, out, T_DIM, D_MODEL, D_MODEL);
}

// Round 9
// 650.454 us; speedup vs baseline: 1.7830x; 1.1195x over previous
//
#include <hip/hip_runtime.h>
#include <hip/hip_bf16.h>
#include <math.h>

// ---------------------------------------------------------------------------
// DeepSeek MLA forward. Round 9:
//  - attn: BACK to monolithic R5 mapping (512 blocks = (h, qt), sequential k,
//    heavy/light paired). R7/R8 split-K scattered co-resident blocks across
//    k-ranges -> L2 temporal locality destroyed (FETCH 35->242 MB). Monolithic
//    restores it. Kept from R6-R8: padded Ps (stride 72), PV V-preload,
//    (256,2) bounds (NOT (256,4): unified VGPR+AGPR cap -> spill, R6).
//  - NEW: ping-pong 24 KB Q+K staging buffers -> 1 barrier per 32-dim chunk
//    (prev-reader drain covered by previous chunk's barrier on other buffer).
//    12 barriers/k-tile vs 17. No partials / no merge kernel.
//  - Score path split-bf16 3-MFMA; post-softmax plain bf16 MFMA.
// ---------------------------------------------------------------------------

#define T_DIM 2048
#define HEADS 16
#define D_MODEL 2048
#define NOPE_D 128
#define ROPE_D 64
#define QKD_D 192
#define VD_D 128
#define QLORA 768
#define KVLORA 512
#define KVFULL_D 576
#define SOFTSCALE -96.0f
#define EPS_RMS 1e-6f

typedef __hip_bfloat16 bf;
typedef __attribute__((ext_vector_type(8))) short bf16x8;
typedef __attribute__((ext_vector_type(4))) float f32x4;

#define GLOAD_LDS16(gptr, lptr)                                               \
    __builtin_amdgcn_global_load_lds(                                         \
        (const __attribute__((address_space(1))) unsigned int*)(gptr),        \
        (__attribute__((address_space(3))) unsigned int*)(lptr), 16, 0, 0)

__device__ __forceinline__ void split2(float v, bf* hi, bf* lo) {
    bf h = __float2bfloat16(v);
    *hi = h;
    *lo = __float2bfloat16(v - __bfloat162float(h));
}

// ---------------------------------------------------------------------------
__global__ __launch_bounds__(256) void cvt_split(
    const float* __restrict__ in, bf* __restrict__ hi, bf* __restrict__ lo, int n)
{
    const int i = (blockIdx.x * 256 + threadIdx.x) * 4;
    if (i >= n) return;
    float4 v = *(const float4*)&in[i];
    float vv[4] = {v.x, v.y, v.z, v.w};
#pragma unroll
    for (int u = 0; u < 4; u++) split2(vv[u], &hi[i + u], &lo[i + u]);
}

__global__ __launch_bounds__(256) void cvt_hi(
    const float* __restrict__ in, bf* __restrict__ hi, int n)
{
    const int i = (blockIdx.x * 256 + threadIdx.x) * 4;
    if (i >= n) return;
    float4 v = *(const float4*)&in[i];
    hi[i + 0] = __float2bfloat16(v.x);
    hi[i + 1] = __float2bfloat16(v.y);
    hi[i + 2] = __float2bfloat16(v.z);
    hi[i + 3] = __float2bfloat16(v.w);
}

// ---------------------------------------------------------------------------
__global__ __launch_bounds__(256) void rmsnorm_cvt(
    const float* __restrict__ in, int ld, int D, const float* __restrict__ w,
    bf* __restrict__ hi, bf* __restrict__ lo)
{
    const int row = blockIdx.x;
    const float* r = in + (size_t)row * ld;
    float ss = 0.0f;
    for (int i = threadIdx.x; i < D; i += 256) { float v = r[i]; ss += v * v; }
#pragma unroll
    for (int o = 32; o > 0; o >>= 1) ss += __shfl_down(ss, o, 64);
    __shared__ float red[4];
    if ((threadIdx.x & 63) == 0) red[threadIdx.x >> 6] = ss;
    __syncthreads();
    ss = red[0] + red[1] + red[2] + red[3];
    const float scale = rsqrtf(ss / (float)D + EPS_RMS);
    for (int i = threadIdx.x; i < D; i += 256) {
        const float v = r[i] * scale * w[i];
        split2(v, &hi[(size_t)row * D + i], &lo[(size_t)row * D + i]);
    }
}

// ---------------------------------------------------------------------------
__global__ __launch_bounds__(256) void rope_k_cvt(
    const float* __restrict__ kvfull, const float* __restrict__ freqs,
    bf* __restrict__ kpeh, bf* __restrict__ kpel)
{
    const int idx = blockIdx.x * 256 + threadIdx.x;   // 65536
    const int i = idx & 31, t = idx >> 5;
    const float f = freqs[t * 32 + i];
    float sn, cs; sincosf(f, &sn, &cs);
    const float x1 = kvfull[(size_t)t * KVFULL_D + KVLORA + 2 * i];
    const float x2 = kvfull[(size_t)t * KVFULL_D + KVLORA + 2 * i + 1];
    split2(x1 * cs - x2 * sn, &kpeh[t * 64 + 2 * i], &kpel[t * 64 + 2 * i]);
    split2(x1 * sn + x2 * cs, &kpeh[t * 64 + 2 * i + 1], &kpel[t * 64 + 2 * i + 1]);
}

// ---------------------------------------------------------------------------
__global__ __launch_bounds__(256) void transpose_v(
    const bf* __restrict__ vh, bf* __restrict__ vT)
{
    __shared__ bf s[32][33];
    const int t0 = blockIdx.x * 32, d0 = blockIdx.y * 32, h = blockIdx.z;
    const int tid = threadIdx.x;
    const int i = tid >> 3, j0 = (tid & 7) * 4;
    const bf* src = vh + ((size_t)(t0 + i) * 16 + h) * 128 + d0 + j0;
#pragma unroll
    for (int u = 0; u < 4; u++) s[i][j0 + u] = src[u];
    __syncthreads();
    const int jj = tid >> 3, i0 = (tid & 7) * 4;
    bf* dst = vT + ((size_t)h * 128 + d0 + jj) * 2048 + t0 + i0;
#pragma unroll
    for (int u = 0; u < 4; u++) dst[u] = s[i0 + u][jj];
}

// ---------------------------------------------------------------------------
// Split-bf16 GEMM (score path), 128x128 tile, 3 MFMAs.
// MODE 1: RoPE on d>=128 + split -> Oh/Ol (q). MODE 2: kn/v split write.
// ---------------------------------------------------------------------------
template <int MODE>
__global__ __launch_bounds__(256) void gemm_split(
    const bf* __restrict__ Ah, const bf* __restrict__ Al,
    const bf* __restrict__ Bh, const bf* __restrict__ Bl,
    const float* __restrict__ freqs,
    float* __restrict__ Cf, bf* __restrict__ Oh, bf* __restrict__ Ol,
    bf* __restrict__ O2, int M, int N, int K)
{
    __shared__ bf sAh[128 * 32], sAl[128 * 32];
    __shared__ bf sBh[128 * 32], sBl[128 * 32];

    const int tid = threadIdx.x;
    const int lane = tid & 63, wave = tid >> 6;
    const int row0 = blockIdx.y * 128, col0 = blockIdx.x * 128;
    const int wm = (wave & 1) * 64, wn = (wave >> 1) * 64;
    const int fr = lane & 15, quad = lane >> 4;

    f32x4 acc[4][4];
#pragma unroll
    for (int i = 0; i < 4; i++)
#pragma unroll
        for (int j = 0; j < 4; j++) acc[i][j] = (f32x4){0.f, 0.f, 0.f, 0.f};

    const int trow = tid >> 2;
    const int tcol = (tid & 3) * 8;
    const size_t ldsoff = (size_t)wave * 1024;

    for (int kt = 0; kt < K; kt += 32) {
        __syncthreads();
        GLOAD_LDS16(Ah + (size_t)(row0 + trow) * K + kt + tcol,      (char*)sAh + ldsoff);
        GLOAD_LDS16(Ah + (size_t)(row0 + 64 + trow) * K + kt + tcol, (char*)sAh + 4096 + ldsoff);
        GLOAD_LDS16(Al + (size_t)(row0 + trow) * K + kt + tcol,      (char*)sAl + ldsoff);
        GLOAD_LDS16(Al + (size_t)(row0 + 64 + trow) * K + kt + tcol, (char*)sAl + 4096 + ldsoff);
        GLOAD_LDS16(Bh + (size_t)(col0 + trow) * K + kt + tcol,      (char*)sBh + ldsoff);
        GLOAD_LDS16(Bh + (size_t)(col0 + 64 + trow) * K + kt + tcol, (char*)sBh + 4096 + ldsoff);
        GLOAD_LDS16(Bl + (size_t)(col0 + trow) * K + kt + tcol,      (char*)sBl + ldsoff);
        GLOAD_LDS16(Bl + (size_t)(col0 + 64 + trow) * K + kt + tcol, (char*)sBl + 4096 + ldsoff);
        __syncthreads();

        bf16x8 a_h[4], a_l[4], b_h[4], b_l[4];
#pragma unroll
        for (int mt = 0; mt < 4; mt++) {
            const int r = (wm + mt * 16 + fr) * 32 + quad * 8;
            a_h[mt] = *(const bf16x8*)&sAh[r];
            a_l[mt] = *(const bf16x8*)&sAl[r];
        }
#pragma unroll
        for (int nt = 0; nt < 4; nt++) {
            const int r = (wn + nt * 16 + fr) * 32 + quad * 8;
            b_h[nt] = *(const bf16x8*)&sBh[r];
            b_l[nt] = *(const bf16x8*)&sBl[r];
        }
#pragma unroll
        for (int mt = 0; mt < 4; mt++)
#pragma unroll
            for (int nt = 0; nt < 4; nt++) {
                acc[mt][nt] = __builtin_amdgcn_mfma_f32_16x16x32_bf16(
                    a_l[mt], b_h[nt], acc[mt][nt], 0, 0, 0);
                acc[mt][nt] = __builtin_amdgcn_mfma_f32_16x16x32_bf16(
                    a_h[mt], b_l[nt], acc[mt][nt], 0, 0, 0);
                acc[mt][nt] = __builtin_amdgcn_mfma_f32_16x16x32_bf16(
                    a_h[mt], b_h[nt], acc[mt][nt], 0, 0, 0);
            }
    }

#pragma unroll
    for (int mt = 0; mt < 4; mt++)
#pragma unroll
        for (int nt = 0; nt < 4; nt++) {
            const int colb = col0 + wn + nt * 16;
            const int col = colb + fr;
            if (MODE == 1) {
                const int d0 = colb % 192;
                const bool rope = (d0 >= 128);
                const int ii = (d0 + fr - 128) >> 1;
#pragma unroll
                for (int r = 0; r < 4; r++) {
                    const int row = row0 + wm + mt * 16 + quad * 4 + r;
                    float v = acc[mt][nt][r];
                    if (rope) {
                        const float other = __shfl_xor(v, 1);
                        float sn, cs; sincosf(freqs[row * 32 + ii], &sn, &cs);
                        v = (fr & 1) ? (other * sn + v * cs) : (v * cs - other * sn);
                    }
                    bf h8, l8; split2(v, &h8, &l8);
                    Oh[(size_t)row * N + col] = h8;
                    Ol[(size_t)row * N + col] = l8;
                }
            } else {
                const int hh = col >> 8;
                const int d = col & 255;
#pragma unroll
                for (int r = 0; r < 4; r++) {
                    const int row = row0 + wm + mt * 16 + quad * 4 + r;
                    const float v = acc[mt][nt][r];
                    if (d < 128) {
                        bf h8, l8; split2(v, &h8, &l8);
                        Oh[(size_t)row * 2048 + hh * 128 + d] = h8;
                        Ol[(size_t)row * 2048 + hh * 128 + d] = l8;
                    } else {
                        O2[(size_t)row * 2048 + hh * 128 + (d - 128)] = __float2bfloat16(v);
                    }
                }
            }
        }
}

// ---------------------------------------------------------------------------
// Split-bf16 GEMM, 64x64 tile (small-N shapes: qa N=768, kvfull N=576).
// ---------------------------------------------------------------------------
__global__ __launch_bounds__(256) void gemm_split64(
    const bf* __restrict__ Ah, const bf* __restrict__ Al,
    const bf* __restrict__ Bh, const bf* __restrict__ Bl,
    float* __restrict__ Cf, int M, int N, int K)
{
    __shared__ bf sAh[64 * 32], sAl[64 * 32];
    __shared__ bf sBh[64 * 32], sBl[64 * 32];

    const int tid = threadIdx.x;
    const int lane = tid & 63, wave = tid >> 6;
    const int row0 = blockIdx.y * 64, col0 = blockIdx.x * 64;
    const int wm = (wave & 1) * 32, wn = (wave >> 1) * 32;
    const int fr = lane & 15, quad = lane >> 4;

    f32x4 acc[2][2];
#pragma unroll
    for (int i = 0; i < 2; i++)
#pragma unroll
        for (int j = 0; j < 2; j++) acc[i][j] = (f32x4){0.f, 0.f, 0.f, 0.f};

    const int trow = tid >> 2;
    const int tcol = (tid & 3) * 8;
    const size_t ldsoff = (size_t)wave * 1024;

    for (int kt = 0; kt < K; kt += 32) {
        __syncthreads();
        GLOAD_LDS16(Ah + (size_t)(row0 + trow) * K + kt + tcol, (char*)sAh + ldsoff);
        GLOAD_LDS16(Al + (size_t)(row0 + trow) * K + kt + tcol, (char*)sAl + ldsoff);
        GLOAD_LDS16(Bh + (size_t)(col0 + trow) * K + kt + tcol, (char*)sBh + ldsoff);
        GLOAD_LDS16(Bl + (size_t)(col0 + trow) * K + kt + tcol, (char*)sBl + ldsoff);
        __syncthreads();

        bf16x8 a_h[2], a_l[2], b_h[2], b_l[2];
#pragma unroll
        for (int mt = 0; mt < 2; mt++) {
            const int r = (wm + mt * 16 + fr) * 32 + quad * 8;
            a_h[mt] = *(const bf16x8*)&sAh[r];
            a_l[mt] = *(const bf16x8*)&sAl[r];
        }
#pragma unroll
        for (int nt = 0; nt < 2; nt++) {
            const int r = (wn + nt * 16 + fr) * 32 + quad * 8;
            b_h[nt] = *(const bf16x8*)&sBh[r];
            b_l[nt] = *(const bf16x8*)&sBl[r];
        }
#pragma unroll
        for (int mt = 0; mt < 2; mt++)
#pragma unroll
            for (int nt = 0; nt < 2; nt++) {
                acc[mt][nt] = __builtin_amdgcn_mfma_f32_16x16x32_bf16(
                    a_l[mt], b_h[nt], acc[mt][nt], 0, 0, 0);
                acc[mt][nt] = __builtin_amdgcn_mfma_f32_16x16x32_bf16(
                    a_h[mt], b_l[nt], acc[mt][nt], 0, 0, 0);
                acc[mt][nt] = __builtin_amdgcn_mfma_f32_16x16x32_bf16(
                    a_h[mt], b_h[nt], acc[mt][nt], 0, 0, 0);
            }
    }

#pragma unroll
    for (int mt = 0; mt < 2; mt++)
#pragma unroll
        for (int nt = 0; nt < 2; nt++)
#pragma unroll
            for (int r = 0; r < 4; r++)
                Cf[(size_t)(row0 + wm + mt * 16 + quad * 4 + r) * N +
                   col0 + wn + nt * 16 + fr] = acc[mt][nt][r];
}

// ---------------------------------------------------------------------------
// Plain bf16 GEMM (post-softmax out-projection): C = A @ B^T, single MFMA.
// ---------------------------------------------------------------------------
__global__ __launch_bounds__(256) void gemm_bf16(
    const bf* __restrict__ Ah, const bf* __restrict__ Bh,
    float* __restrict__ Cf, int M, int N, int K)
{
    __shared__ bf sAh[128 * 32];
    __shared__ bf sBh[128 * 32];

    const int tid = threadIdx.x;
    const int lane = tid & 63, wave = tid >> 6;
    const int row0 = blockIdx.y * 128, col0 = blockIdx.x * 128;
    const int wm = (wave & 1) * 64, wn = (wave >> 1) * 64;
    const int fr = lane & 15, quad = lane >> 4;

    f32x4 acc[4][4];
#pragma unroll
    for (int i = 0; i < 4; i++)
#pragma unroll
        for (int j = 0; j < 4; j++) acc[i][j] = (f32x4){0.f, 0.f, 0.f, 0.f};

    const int trow = tid >> 2;
    const int tcol = (tid & 3) * 8;
    const size_t ldsoff = (size_t)wave * 1024;

    for (int kt = 0; kt < K; kt += 32) {
        __syncthreads();
        GLOAD_LDS16(Ah + (size_t)(row0 + trow) * K + kt + tcol,      (char*)sAh + ldsoff);
        GLOAD_LDS16(Ah + (size_t)(row0 + 64 + trow) * K + kt + tcol, (char*)sAh + 4096 + ldsoff);
        GLOAD_LDS16(Bh + (size_t)(col0 + trow) * K + kt + tcol,      (char*)sBh + ldsoff);
        GLOAD_LDS16(Bh + (size_t)(col0 + 64 + trow) * K + kt + tcol, (char*)sBh + 4096 + ldsoff);
        __syncthreads();

        bf16x8 a_h[4], b_h[4];
#pragma unroll
        for (int mt = 0; mt < 4; mt++)
            a_h[mt] = *(const bf16x8*)&sAh[(wm + mt * 16 + fr) * 32 + quad * 8];
#pragma unroll
        for (int nt = 0; nt < 4; nt++)
            b_h[nt] = *(const bf16x8*)&sBh[(wn + nt * 16 + fr) * 32 + quad * 8];
#pragma unroll
        for (int mt = 0; mt < 4; mt++)
#pragma unroll
            for (int nt = 0; nt < 4; nt++)
                acc[mt][nt] = __builtin_amdgcn_mfma_f32_16x16x32_bf16(
                    a_h[mt], b_h[nt], acc[mt][nt], 0, 0, 0);
    }

#pragma unroll
    for (int mt = 0; mt < 4; mt++)
#pragma unroll
        for (int nt = 0; nt < 4; nt++)
#pragma unroll
            for (int r = 0; r < 4; r++)
                Cf[(size_t)(row0 + wm + mt * 16 + quad * 4 + r) * N +
                   col0 + wn + nt * 16 + fr] = acc[mt][nt][r];
}

// ---------------------------------------------------------------------------
// Monolithic MFMA flash attention. 512 blocks = (h, qt), heavy/light paired.
// Per 128-key k-tile: ping-pong staged S (6 chunks x 1 barrier), fp32 online
// softmax, PV with padded Ps (stride 72) + preloaded V pairs. Writes y bf16.
// LDS 60.4 KB -> 2 blocks/CU. (256,2): (256,4) spills (R6). Sequential-k
// co-residency is what keeps FETCH at ~35 MB (R5) vs 242 MB (split-K, R7/8).
// ---------------------------------------------------------------------------
__global__ __launch_bounds__(256, 2) void attn_mfma(
    const bf* __restrict__ qh, const bf* __restrict__ ql,
    const bf* __restrict__ knh, const bf* __restrict__ knl,
    const bf* __restrict__ kpeh, const bf* __restrict__ kpel,
    const bf* __restrict__ vT, bf* __restrict__ yh)
{
    const int bid = blockIdx.x;
    const int h = bid & 15;
    const int qt = (bid < 256) ? (31 - (bid >> 4)) : ((bid - 256) >> 4);

    const int tid = threadIdx.x;
    const int lane = tid & 63, wave = tid >> 6;
    const int fr = lane & 15, quad = lane >> 4;
    const int wn = wave * 32;

    // buf0 @0, buf1 @24576 (each: Qh 0 / Ql 4096 / Kh 8192 / Kl 16384)
    // sVt aliases buf0[0:16384] during PV. Ps @49152 ([64][72] bf16).
    __shared__ __align__(16) char smem[60416];
    bf* Ps  = (bf*)(smem + 49152);
    float* redM = (float*)(smem + 58368); // [64][4]
    float* redS = (float*)(smem + 59392); // [64][4]

    float m_i[16], l_i[16], al[16];
    f32x4 O[4][2];
#pragma unroll
    for (int i = 0; i < 16; i++) { m_i[i] = -INFINITY; l_i[i] = 0.0f; }
#pragma unroll
    for (int mt = 0; mt < 4; mt++)
#pragma unroll
        for (int nt = 0; nt < 2; nt++) O[mt][nt] = (f32x4){0.f, 0.f, 0.f, 0.f};

    const int q0 = qt * 64;
    const int nkt = ((qt + 1) * 64 + 127) >> 7;
    const int trow = tid >> 2, tcol = (tid & 3) * 8;
    const size_t loff = (size_t)wave * 1024;

    for (int kt = 0; kt < nkt; kt++) {
        const int k0 = kt * 128;
        f32x4 S[4][2];
#pragma unroll
        for (int mt = 0; mt < 4; mt++)
#pragma unroll
            for (int nt = 0; nt < 2; nt++) S[mt][nt] = (f32x4){0.f, 0.f, 0.f, 0.f};

        // leading barrier: prior k-tile's PV readers of buf0 (sVt alias) done
        __syncthreads();

        // ---- S = Q.K^T over 192 dims: 6 chunks, ping-pong, 1 barrier each --
        for (int ch = 0; ch < 6; ch++) {
            const int d0 = ch * 32;
            char* buf = smem + ((ch & 1) ? 24576 : 0);
            GLOAD_LDS16(qh + ((size_t)(q0 + trow) * 16 + h) * 192 + d0 + tcol, buf + loff);
            GLOAD_LDS16(ql + ((size_t)(q0 + trow) * 16 + h) * 192 + d0 + tcol, buf + 4096 + loff);
            if (d0 < 128) {
                GLOAD_LDS16(knh + ((size_t)(k0 + trow) * 16 + h) * 128 + d0 + tcol,      buf + 8192 + loff);
                GLOAD_LDS16(knh + ((size_t)(k0 + 64 + trow) * 16 + h) * 128 + d0 + tcol, buf + 12288 + loff);
                GLOAD_LDS16(knl + ((size_t)(k0 + trow) * 16 + h) * 128 + d0 + tcol,      buf + 16384 + loff);
                GLOAD_LDS16(knl + ((size_t)(k0 + 64 + trow) * 16 + h) * 128 + d0 + tcol, buf + 20480 + loff);
            } else {
                GLOAD_LDS16(kpeh + (size_t)(k0 + trow) * 64 + (d0 - 128) + tcol,      buf + 8192 + loff);
                GLOAD_LDS16(kpeh + (size_t)(k0 + 64 + trow) * 64 + (d0 - 128) + tcol, buf + 12288 + loff);
                GLOAD_LDS16(kpel + (size_t)(k0 + trow) * 64 + (d0 - 128) + tcol,      buf + 16384 + loff);
                GLOAD_LDS16(kpel + (size_t)(k0 + 64 + trow) * 64 + (d0 - 128) + tcol, buf + 20480 + loff);
            }
            __syncthreads();

            const bf* sQh = (const bf*)buf;
            const bf* sQl = (const bf*)(buf + 4096);
            const bf* sKh = (const bf*)(buf + 8192);
            const bf* sKl = (const bf*)(buf + 16384);
            bf16x8 a_h[4], a_l[4], b_h[2], b_l[2];
#pragma unroll
            for (int mt = 0; mt < 4; mt++) {
                const int r = (mt * 16 + fr) * 32 + quad * 8;
                a_h[mt] = *(const bf16x8*)&sQh[r];
                a_l[mt] = *(const bf16x8*)&sQl[r];
            }
#pragma unroll
            for (int nt = 0; nt < 2; nt++) {
                const int r = (wn + nt * 16 + fr) * 32 + quad * 8;
                b_h[nt] = *(const bf16x8*)&sKh[r];
                b_l[nt] = *(const bf16x8*)&sKl[r];
            }
#pragma unroll
            for (int mt = 0; mt < 4; mt++)
#pragma unroll
                for (int nt = 0; nt < 2; nt++) {
                    S[mt][nt] = __builtin_amdgcn_mfma_f32_16x16x32_bf16(
                        a_l[mt], b_h[nt], S[mt][nt], 0, 0, 0);
                    S[mt][nt] = __builtin_amdgcn_mfma_f32_16x16x32_bf16(
                        a_h[mt], b_l[nt], S[mt][nt], 0, 0, 0);
                    S[mt][nt] = __builtin_amdgcn_mfma_f32_16x16x32_bf16(
                        a_h[mt], b_h[nt], S[mt][nt], 0, 0, 0);
                }
        }

        // ---- online softmax (fp32, block-wide row reductions) ----
#pragma unroll
        for (int mt = 0; mt < 4; mt++)
#pragma unroll
            for (int rr = 0; rr < 4; rr++) {
                const int ri = mt * 16 + quad * 4 + rr;
                const int rowg = q0 + ri;
                float v0 = S[mt][0][rr] * SOFTSCALE;
                float v1 = S[mt][1][rr] * SOFTSCALE;
                if (k0 + wn + fr > rowg)      v0 = -INFINITY;
                if (k0 + wn + 16 + fr > rowg) v1 = -INFINITY;
                S[mt][0][rr] = v0; S[mt][1][rr] = v1;
                float pm = fmaxf(v0, v1);
#pragma unroll
                for (int o = 1; o < 16; o <<= 1) pm = fmaxf(pm, __shfl_xor(pm, o, 64));
                if (fr == 0) redM[ri * 4 + wave] = pm;
            }
        __syncthreads();
#pragma unroll
        for (int mt = 0; mt < 4; mt++)
#pragma unroll
            for (int rr = 0; rr < 4; rr++) {
                const int idx = mt * 4 + rr;
                const int ri = mt * 16 + quad * 4 + rr;
                const float4 g = *(const float4*)&redM[ri * 4];
                const float gm = fmaxf(fmaxf(g.x, g.y), fmaxf(g.z, g.w));
                const float mn = fmaxf(m_i[idx], gm);
                al[idx] = __expf(m_i[idx] - mn);
                m_i[idx] = mn;
                const float p0 = __expf(S[mt][0][rr] - mn);
                const float p1 = __expf(S[mt][1][rr] - mn);
                S[mt][0][rr] = p0; S[mt][1][rr] = p1;   // keep p for PV store
                float ps = p0 + p1;
#pragma unroll
                for (int o = 1; o < 16; o <<= 1) ps += __shfl_xor(ps, o, 64);
                if (fr == 0) redS[ri * 4 + wave] = ps;
            }
#pragma unroll
        for (int mt = 0; mt < 4; mt++)
#pragma unroll
            for (int nt = 0; nt < 2; nt++)
#pragma unroll
                for (int rr = 0; rr < 4; rr++) O[mt][nt][rr] *= al[mt * 4 + rr];
        __syncthreads();
#pragma unroll
        for (int mt = 0; mt < 4; mt++)
#pragma unroll
            for (int rr = 0; rr < 4; rr++) {
                const int idx = mt * 4 + rr;
                const int ri = mt * 16 + quad * 4 + rr;
                const float4 s4 = *(const float4*)&redS[ri * 4];
                l_i[idx] = l_i[idx] * al[idx] + (s4.x + s4.y + s4.z + s4.w);
            }

        // ---- PV: two 64-key halves; both 32-key V chunks preloaded ----
        bf* sVt = (bf*)smem;   // aliases buf0 (dead during PV)
#pragma unroll
        for (int half = 0; half < 2; half++) {
            if (half) __syncthreads();   // prior Ps/sVt readers done
            if ((wave >> 1) == half) {
                const int kc = wn - half * 64;   // 0 or 32
#pragma unroll
                for (int mt = 0; mt < 4; mt++)
#pragma unroll
                    for (int rr = 0; rr < 4; rr++) {
                        const int ri = mt * 16 + quad * 4 + rr;
                        Ps[ri * 72 + kc + fr]      = __float2bfloat16(S[mt][0][rr]);
                        Ps[ri * 72 + kc + 16 + fr] = __float2bfloat16(S[mt][1][rr]);
                    }
            }
            const int kb = k0 + half * 64;
            GLOAD_LDS16(vT + ((size_t)(h * 128 + trow)) * 2048 + kb + tcol,           (char*)sVt + loff);
            GLOAD_LDS16(vT + ((size_t)(h * 128 + 64 + trow)) * 2048 + kb + tcol,      (char*)sVt + 4096 + loff);
            GLOAD_LDS16(vT + ((size_t)(h * 128 + trow)) * 2048 + kb + 32 + tcol,      (char*)sVt + 8192 + loff);
            GLOAD_LDS16(vT + ((size_t)(h * 128 + 64 + trow)) * 2048 + kb + 32 + tcol, (char*)sVt + 12288 + loff);
            __syncthreads();
#pragma unroll
            for (int vc = 0; vc < 2; vc++) {
                bf16x8 ap[4], bv[2];
#pragma unroll
                for (int mt = 0; mt < 4; mt++)
                    ap[mt] = *(const bf16x8*)&Ps[(mt * 16 + fr) * 72 + vc * 32 + quad * 8];
#pragma unroll
                for (int nt = 0; nt < 2; nt++)
                    bv[nt] = *(const bf16x8*)&sVt[vc * 4096 + (wn + nt * 16 + fr) * 32 + quad * 8];
#pragma unroll
                for (int mt = 0; mt < 4; mt++)
#pragma unroll
                    for (int nt = 0; nt < 2; nt++)
                        O[mt][nt] = __builtin_amdgcn_mfma_f32_16x16x32_bf16(
                            ap[mt], bv[nt], O[mt][nt], 0, 0, 0);
            }
        }
    }

    // ---- epilogue: y = O / l (bf16) ----
#pragma unroll
    for (int mt = 0; mt < 4; mt++)
#pragma unroll
        for (int rr = 0; rr < 4; rr++) {
            const float inv = 1.0f / l_i[mt * 4 + rr];
            const int row = q0 + mt * 16 + quad * 4 + rr;
#pragma unroll
            for (int nt = 0; nt < 2; nt++)
                yh[((size_t)row * 16 + h) * 128 + wn + nt * 16 + fr] =
                    __float2bfloat16(O[mt][nt][rr] * inv);
        }
}

// ---------------------------------------------------------------------------
// Workspace (peak < 85 MB):
//  A  @0        : xh(8.39) xl(8.39) -> yh@0, vT@8.39
//  AR @16.78    : (16.78) GEMM temporaries -> woh
//  persistent   : qh@33.55 ql@46.14 knh@58.72 knl@67.11 vh@75.50
//                 kpeh@83.89 kpel@84.15
// ---------------------------------------------------------------------------
extern "C" void kernel_launch(void* const* d_in, const int* in_sizes, int n_in,
                              void* d_out, int out_size, void* d_ws, size_t ws_size,
                              hipStream_t stream)
{
    const float* x        = (const float*)d_in[0];
    const float* freqs    = (const float*)d_in[1];
    const float* wq_a     = (const float*)d_in[3];
    const float* q_norm_w = (const float*)d_in[4];
    const float* wq_b     = (const float*)d_in[5];
    const float* wkv_a    = (const float*)d_in[6];
    const float* kv_norm_w= (const float*)d_in[7];
    const float* wkv_b    = (const float*)d_in[8];
    const float* wo       = (const float*)d_in[9];
    float* out            = (float*)d_out;

    char* ws = (char*)d_ws;
    bf* xh = (bf*)(ws);
    bf* xl = (bf*)(ws + 8388608);
    bf* yh = (bf*)(ws);                   // after x dead
    bf* vT = (bf*)(ws + 8388608);         // after x dead
    char* AR = ws + 16777216;
    bf*    wah    = (bf*)(AR);
    bf*    wal    = (bf*)(AR + 3145728);
    float* qa     = (float*)(AR + 6291456);
    bf*    qah    = (bf*)(AR);
    bf*    qal    = (bf*)(AR + 3145728);
    bf*    wbh    = (bf*)(AR + 6291456);
    bf*    wbl    = (bf*)(AR + 11010048);
    bf*    kah    = (bf*)(AR);
    bf*    kal    = (bf*)(AR + 2359296);
    float* kvfull = (float*)(AR + 4718592);
    bf*    ckvh   = (bf*)(AR + 9437184);
    bf*    ckvl   = (bf*)(AR + 11534336);
    bf*    wvh    = (bf*)(AR);
    bf*    wvl    = (bf*)(AR + 4194304);
    bf*    woh    = (bf*)(AR);
    bf* qh   = (bf*)(ws + 33554432);
    bf* ql   = (bf*)(ws + 46137344);
    bf* knh  = (bf*)(ws + 58720256);
    bf* knl  = (bf*)(ws + 67108864);
    bf* vh   = (bf*)(ws + 75497472);
    bf* kpeh = (bf*)(ws + 83886080);
    bf* kpel = (bf*)(ws + 84148224);

    dim3 blk(256);

    cvt_split<<<4096, blk, 0, stream>>>(x, xh, xl, D_MODEL * D_MODEL);
    cvt_split<<<1536, blk, 0, stream>>>(wq_a, wah, wal, QLORA * D_MODEL);
    gemm_split64<<<dim3(12, 32), blk, 0, stream>>>(
        xh, xl, wah, wal, qa, T_DIM, QLORA, D_MODEL);
    rmsnorm_cvt<<<T_DIM, blk, 0, stream>>>(qa, QLORA, QLORA, q_norm_w, qah, qal);
    cvt_split<<<2304, blk, 0, stream>>>(wq_b, wbh, wbl, 3072 * QLORA);
    gemm_split<1><<<dim3(24, 16), blk, 0, stream>>>(
        qah, qal, wbh, wbl, freqs, nullptr, qh, ql, nullptr,
        T_DIM, 3072, QLORA);
    cvt_split<<<1152, blk, 0, stream>>>(wkv_a, kah, kal, KVFULL_D * D_MODEL);
    gemm_split64<<<dim3(9, 32), blk, 0, stream>>>(
        xh, xl, kah, kal, kvfull, T_DIM, KVFULL_D, D_MODEL);
    rope_k_cvt<<<256, blk, 0, stream>>>(kvfull, freqs, kpeh, kpel);
    rmsnorm_cvt<<<T_DIM, blk, 0, stream>>>(kvfull, KVFULL_D, KVLORA, kv_norm_w, ckvh, ckvl);
    cvt_split<<<2048, blk, 0, stream>>>(wkv_b, wvh, wvl, 4096 * KVLORA);
    gemm_split<2><<<dim3(32, 16), blk, 0, stream>>>(
        ckvh, ckvl, wvh, wvl, nullptr, nullptr, knh, knl, vh,
        T_DIM, 4096, KVLORA);
    transpose_v<<<dim3(64, 4, 16), blk, 0, stream>>>(vh, vT);
    attn_mfma<<<dim3(512), blk, 0, stream>>>(
        qh, ql, knh, knl, kpeh, kpel, vT, yh);
    cvt_hi<<<4096, blk, 0, stream>>>(wo, woh, D_MODEL * D_MODEL);
    gemm_bf16<<<dim3(16, 16), blk, 0, stream>>>(
        yh, woh, out, T_DIM, D_MODEL, D_MODEL);
}